// Round 15
// baseline (18188.899 us; speedup 1.0000x reference)
//
#include <hip/hip_runtime.h>
#include <hip/hip_bf16.h>

typedef _Float16 f16x8 __attribute__((ext_vector_type(8)));
typedef float f32x4 __attribute__((ext_vector_type(4)));

#define DI static __device__ __forceinline__

constexpr int Bn = 64, Fn = 128, Tn = 1024, Hn = 256, NTn = 11;
constexpr int BT = Bn * Tn;       // 65536
constexpr int Gn = 4 * Hn;        // 1024
constexpr int Sn = 4 * Tn;        // 4096

// ---------------- device global buffers (no d_ws use) ----------------
__device__ __align__(16) _Float16 g_xt_h[BT * Fn];
__device__ __align__(16) _Float16 g_xt_l[BT * Fn];
__device__ __align__(16) _Float16 g_f0_h[BT * 512];
__device__ __align__(16) _Float16 g_f0_l[BT * 512];
__device__ __align__(16) _Float16 g_f1_h[BT * 512];
__device__ __align__(16) _Float16 g_f1_l[BT * 512];
__device__ __align__(16) float    g_xg[(size_t)BT * 2048];   // 512MB, reused per layer
__device__ __align__(16) _Float16 g_whh_h[4 * Gn * Hn];      // fragment-swizzled
__device__ __align__(16) _Float16 g_whh_l[4 * Gn * Hn];
__device__ __align__(16) _Float16 g_wih0_h[2048 * Fn];
__device__ __align__(16) _Float16 g_wih0_l[2048 * Fn];
__device__ __align__(16) _Float16 g_wih1_h[2048 * 512];
__device__ __align__(16) _Float16 g_wih1_l[2048 * 512];
__device__ __align__(16) _Float16 g_wout_h[48 * 512];
__device__ __align__(16) _Float16 g_wout_l[48 * 512];
__device__ float g_b0[2048], g_b1[2048], g_bo[48];
__device__ float g_em[BT * 44];
__device__ __align__(4) unsigned char g_hist[(size_t)Sn * Bn * NTn];
__device__ int   g_rev[BT];
__device__ float g_llh[Bn];
__device__ int   g_last[Bn];
// cross-wg h staging: [parity][bg][d][fragidx] packed (hi | lo<<16)
__device__ unsigned int g_hxs[2][4][2][4096];
// per-producer half-flags: [layer][bg][d][prod][hm][16 ints pad = 64B/flag]
__device__ int g_syncp[2][4][2][8][2][16];

DI f32x4 mfma_(f16x8 a, f16x8 b, f32x4 c) {
  return __builtin_amdgcn_mfma_f32_16x16x32_f16(a, b, c, 0, 0, 0);
}
DI float sigf(float x) { return 1.f / (1.f + __expf(-x)); }
DI float tanh_(float x) { return 1.f - 2.f / (1.f + __expf(2.f * x)); }

// ---------------- prep kernels ----------------
__global__ void k_zinit() {
  int i = blockIdx.x * 256 + threadIdx.x;
  if (i < 2 * 4 * 2 * 8 * 2 * 16) ((int*)g_syncp)[i] = 0;
}

__global__ void k_split(const float* __restrict__ src, int which, int off, int n) {
  int i = blockIdx.x * 256 + threadIdx.x;
  if (i >= n) return;
  float v = src[i];
  _Float16 h = (_Float16)v;
  _Float16 l = (_Float16)(v - (float)h);
  _Float16 *H, *L;
  switch (which) {
    case 1:  H = g_wih0_h; L = g_wih0_l; break;
    case 2:  H = g_wih1_h; L = g_wih1_l; break;
    default: H = g_wout_h; L = g_wout_l; break;
  }
  H[off + i] = h; L[off + i] = l;
}

// W_hh -> fragment-contiguous swizzle: idx = (((nt*8 + kc)*64 + lane)*8 + j)
// holds W[nt*16 + (lane&15)][kc*32 + (lane>>4)*8 + j]
__global__ void k_wswz(const float* __restrict__ w0, const float* __restrict__ w1,
                       const float* __restrict__ w2, const float* __restrict__ w3) {
  int i = blockIdx.x * 256 + threadIdx.x;
  if (i >= 4 * Gn * Hn) return;
  int mat = i >> 18;
  int e = i & 262143;
  int nt = e >> 12, rem = e & 4095;
  int kc = rem >> 9;
  int rem2 = rem & 511;
  int lane = rem2 >> 3, j = rem2 & 7;
  int row = nt * 16 + (lane & 15);
  int col = kc * 32 + (lane >> 4) * 8 + j;
  const float* src = mat == 0 ? w0 : mat == 1 ? w1 : mat == 2 ? w2 : w3;
  float v = src[row * Hn + col];
  _Float16 h = (_Float16)v;
  g_whh_h[i] = h;
  g_whh_l[i] = (_Float16)(v - (float)h);
}

__global__ void k_copy(const float* __restrict__ src, int which, int off, int n) {
  int i = blockIdx.x * 256 + threadIdx.x;
  if (i >= n) return;
  float* D = which == 0 ? g_b0 : which == 1 ? g_b1 : g_bo;
  D[off + i] = src[i];
}

__global__ void k_pad() {
  int i = blockIdx.x * 256 + threadIdx.x;
  if (i < 48 * 512 - 44 * 512) {            // zero pad rows 44..47 of w_out
    g_wout_h[44 * 512 + i] = (_Float16)0.f;
    g_wout_l[44 * 512 + i] = (_Float16)0.f;
  }
  if (i < 4) g_bo[44 + i] = 0.f;
}

__global__ void k_rev(const int* __restrict__ lengths) {
  int i = blockIdx.x * 256 + threadIdx.x;
  if (i >= BT) return;
  int b = i >> 10, t = i & 1023;
  int len = lengths[b];
  int r = (t < len) ? (len - 1 - t) : t;
  g_rev[i] = (b << 10) | r;
}

// x (B,F,T) -> xt rows (b*T+t, d) split to f16 hi/lo
__global__ void k_xpose(const float* __restrict__ x) {
  __shared__ float tile[32][33];
  int t0 = blockIdx.x * 32, d0 = blockIdx.y * 32, b = blockIdx.z;
  int tx = threadIdx.x, ty = threadIdx.y;
  #pragma unroll
  for (int i = 0; i < 4; i++) {
    int d = d0 + ty + i * 8;
    tile[ty + i * 8][tx] = x[((size_t)b * Fn + d) * Tn + t0 + tx];
  }
  __syncthreads();
  #pragma unroll
  for (int i = 0; i < 4; i++) {
    int t = t0 + ty + i * 8;
    float v = tile[tx][ty + i * 8];
    _Float16 h = (_Float16)v;
    size_t o = ((size_t)b * Tn + t) * Fn + d0 + tx;
    g_xt_h[o] = h;
    g_xt_l[o] = (_Float16)(v - (float)h);
  }
}

// ---------------- generic dual-f16 MFMA GEMM ----------------
// SEL: 0 = proj layer0 (A=xt,K=128), 1 = proj layer1 (A=f0,K=512), 2 = emissions (A=f1,N=48->44)
template <int SEL, int NPL>
__global__ __launch_bounds__(256) void k_gemm() {
  constexpr int KD = SEL == 0 ? 128 : 512;
  constexpr int WM = SEL == 2 ? 4 : 2;
  constexpr int WN = SEL == 2 ? 1 : 2;
  constexpr int MW = SEL == 2 ? 2 : 4;
  constexpr int NW = SEL == 2 ? 3 : 4;
  constexpr int LDO = SEL == 2 ? 44 : 2048;
  constexpr int NCOL = SEL == 2 ? 44 : 2048;
  constexpr int NSPLIT = SEL == 2 ? (1 << 30) : 1024;
  const _Float16* Ah = SEL == 0 ? g_xt_h : SEL == 1 ? g_f0_h : g_f1_h;
  const _Float16* Al = SEL == 0 ? g_xt_l : SEL == 1 ? g_f0_l : g_f1_l;
  const _Float16* Bh = SEL == 0 ? g_wih0_h : SEL == 1 ? g_wih1_h : g_wout_h;
  const _Float16* Bl = SEL == 0 ? g_wih0_l : SEL == 1 ? g_wih1_l : g_wout_l;
  const float* bias = SEL == 0 ? g_b0 : SEL == 1 ? g_b1 : g_bo;
  float* out = SEL == 2 ? g_em : g_xg;

  const int lane = threadIdx.x & 63, wv = threadIdx.x >> 6;
  const int wm = wv / WN, wn = wv % WN;
  const int c = lane & 15, q = lane >> 4;
  const int bm0 = blockIdx.x * (WM * MW * 16);
  const int bn0 = blockIdx.y * (WN * NW * 16);
  const bool bw = bn0 >= NSPLIT;   // backward-direction column block -> gathered A rows
  int arow[MW];
  #pragma unroll
  for (int mi = 0; mi < MW; mi++) {
    int r = bm0 + (wm * MW + mi) * 16 + c;
    arow[mi] = bw ? g_rev[r] : r;
  }
  f32x4 acc[MW][NW];
  #pragma unroll
  for (int mi = 0; mi < MW; mi++)
    #pragma unroll
    for (int ni = 0; ni < NW; ni++) acc[mi][ni] = f32x4{0.f, 0.f, 0.f, 0.f};

  for (int kc = 0; kc < KD / 32; kc++) {
    const int k = kc * 32 + q * 8;
    f16x8 ah[MW], al[MW], bh[NW], bl[NW];
    #pragma unroll
    for (int mi = 0; mi < MW; mi++) {
      ah[mi] = *(const f16x8*)(Ah + (size_t)arow[mi] * KD + k);
      if constexpr (NPL > 1) al[mi] = *(const f16x8*)(Al + (size_t)arow[mi] * KD + k);
    }
    #pragma unroll
    for (int ni = 0; ni < NW; ni++) {
      int n = bn0 + (wn * NW + ni) * 16 + c;
      bh[ni] = *(const f16x8*)(Bh + (size_t)n * KD + k);
      if constexpr (NPL > 1) bl[ni] = *(const f16x8*)(Bl + (size_t)n * KD + k);
    }
    #pragma unroll
    for (int mi = 0; mi < MW; mi++)
      #pragma unroll
      for (int ni = 0; ni < NW; ni++) {
        acc[mi][ni] = mfma_(ah[mi], bh[ni], acc[mi][ni]);
        if constexpr (NPL > 1) {
          acc[mi][ni] = mfma_(ah[mi], bl[ni], acc[mi][ni]);
          acc[mi][ni] = mfma_(al[mi], bh[ni], acc[mi][ni]);
        }
      }
  }
  #pragma unroll
  for (int mi = 0; mi < MW; mi++)
    #pragma unroll
    for (int ni = 0; ni < NW; ni++) {
      int col = bn0 + (wn * NW + ni) * 16 + c;
      if (col < NCOL) {
        int row0 = bm0 + (wm * MW + mi) * 16 + q * 4;
        float bv = bias[col];
        #pragma unroll
        for (int r = 0; r < 4; r++)
          out[(size_t)(row0 + r) * LDO + col] = acc[mi][ni][r] + bv;
      }
    }
}

// ---------------- LSTM recurrence: dual-chain oct, fence-free protocol ----------------
// 8 wgs per (bg-pair, dir). Each wg runs TWO chains (bgA=2bp, bgB=2bp+1) sharing W.
// Per superstep: MFMA A -> BA1 -> {g==0: nonlin A, staged stores A, wave-local drain,
// post flagA, off-path fh/fl A} while all waves then do MFMA B -> BB1 -> {g==0:
// nonlin B, post flagB, fh/fl B} ; wave 7 polls A-flags (lanes 0-15) and B-flags
// (lanes 16-31) -> B3 -> single-RTT read of BOTH staged chunks (8 concurrent u64
// loads) -> B4. Chain B's compute hides chain A's exchange RTT. All atomics RELAXED
// agent-scope (LLC-serviced, no cache-maintenance); wave-local vmcnt(0) before each
// flag post guarantees staged data acked at LLC. Safety: per-chain transitive-B4
// argument as before (flag t+2 implies producer passed B4(t) -> slot reads done).
// LDS: W kc0..6 (112KB) + 4 h-buffers (32KB) + gbufA/B (12KB) = 156KB; kc7 in VGPRs.
__global__ __launch_bounds__(512, 1) void k_rec5(const float* __restrict__ h0,
                                                 const float* __restrict__ c0, int layer) {
  __shared__ __align__(16) _Float16 Wh_l[8][7][512];      // 56 KB
  __shared__ __align__(16) _Float16 Wl_l[8][7][512];      // 56 KB
  __shared__ __align__(16) _Float16 lhA[4096], llA[4096]; // 16 KB
  __shared__ __align__(16) _Float16 lhB[4096], llB[4096]; // 16 KB
  __shared__ float gbuf[2][2][3][16][16];                 // 12 KB [chain][hm][g-1]
  const int tid = threadIdx.x, lane = tid & 63, w = tid >> 6;  // 8 waves
  const int c = lane & 15, q = lane >> 4;
  const int bp = blockIdx.x, d = blockIdx.y, s = blockIdx.z;
  const int bgA = 2 * bp, bgB = 2 * bp + 1;
  const int dirIdx = layer * 2 + d;
  const int g = w >> 1, hm = w & 1;
  const int m = 2 * s + hm;            // unit-tile 0..15
  const int nt = g * 16 + m;           // gate tile 0..63
  const int u = m * 16 + c;            // global unit 0..255
  const _Float16* whp = g_whh_h + (size_t)dirIdx * (Gn * Hn);
  const _Float16* wlp = g_whh_l + (size_t)dirIdx * (Gn * Hn);
  _Float16* fh = layer ? g_f1_h : g_f0_h;
  _Float16* fl = layer ? g_f1_l : g_f0_l;
  const float* h0pA = h0 + ((size_t)dirIdx * Bn + bgA * 16) * Hn;
  const float* c0pA = c0 + ((size_t)dirIdx * Bn + bgA * 16) * Hn;
  const float* h0pB = h0 + ((size_t)dirIdx * Bn + bgB * 16) * Hn;
  const float* c0pB = c0 + ((size_t)dirIdx * Bn + bgB * 16) * Hn;

  // W slice: kc 0..6 -> LDS (once); kc 7 -> pinned VGPRs
  #pragma unroll
  for (int kc = 0; kc < 7; kc++) {
    *(f16x8*)&Wh_l[w][kc][lane * 8] =
        *(const f16x8*)(whp + ((size_t)(nt * 8 + kc) * 64 + lane) * 8);
    *(f16x8*)&Wl_l[w][kc][lane * 8] =
        *(const f16x8*)(wlp + ((size_t)(nt * 8 + kc) * 64 + lane) * 8);
  }
  f16x8 Wh7 = *(const f16x8*)(whp + ((size_t)(nt * 8 + 7) * 64 + lane) * 8);
  f16x8 Wl7 = *(const f16x8*)(wlp + ((size_t)(nt * 8 + 7) * 64 + lane) * 8);
  asm volatile("" : "+v"(Wh7), "+v"(Wl7));

  // h0 -> fragment LDS for both chains
  for (int i = tid; i < 4096; i += 512) {
    int j = i & 7, ln = (i >> 3) & 63, kc = i >> 9;
    int row = ln & 15, uu = kc * 32 + ((ln >> 4) * 8) + j;
    float vA = h0pA[row * Hn + uu];
    _Float16 hA = (_Float16)vA;
    lhA[i] = hA;
    llA[i] = (_Float16)(vA - (float)hA);
    float vB = h0pB[row * Hn + uu];
    _Float16 hB = (_Float16)vB;
    lhB[i] = hB;
    llB[i] = (_Float16)(vB - (float)hB);
  }
  float cregA[4], cregB[4];
  if (g == 0) {
    #pragma unroll
    for (int r = 0; r < 4; r++) {
      cregA[r] = c0pA[(4 * q + r) * Hn + u];
      cregB[r] = c0pB[(4 * q + r) * Hn + u];
    }
  }
  size_t xoffA[4], xoffB[4];
  #pragma unroll
  for (int r = 0; r < 4; r++) {
    xoffA[r] = ((size_t)(bgA * 16 + 4 * q + r) * Tn) * 2048 + (size_t)d * 1024;
    xoffB[r] = ((size_t)(bgB * 16 + 4 * q + r) * Tn) * 2048 + (size_t)d * 1024;
  }
  const int col = g * 256 + u;
  const int fb = (((u >> 5) * 64 + ((u >> 3) & 3) * 16) * 8) + (u & 7);

  float xgA[4], xgB[4];
  #pragma unroll
  for (int r = 0; r < 4; r++) {
    xgA[r] = g_xg[xoffA[r] + col];
    xgB[r] = g_xg[xoffB[r] + col];
  }
  __syncthreads();

  for (int t = 0; t < Tn; t++) {
    const bool more = (t + 1 < Tn);
    // ================= chain A compute =================
    f32x4 accA;
    #pragma unroll
    for (int r = 0; r < 4; r++) accA[r] = xgA[r];
    #pragma unroll
    for (int kc = 0; kc < 7; kc++) {
      f16x8 ah = *(const f16x8*)(lhA + (kc * 64 + lane) * 8);
      f16x8 al = *(const f16x8*)(llA + (kc * 64 + lane) * 8);
      f16x8 wh = *(const f16x8*)&Wh_l[w][kc][lane * 8];
      f16x8 wl = *(const f16x8*)&Wl_l[w][kc][lane * 8];
      accA = mfma_(ah, wh, accA);
      accA = mfma_(ah, wl, accA);
      accA = mfma_(al, wh, accA);
    }
    {
      f16x8 ah = *(const f16x8*)(lhA + (7 * 64 + lane) * 8);
      f16x8 al = *(const f16x8*)(llA + (7 * 64 + lane) * 8);
      accA = mfma_(ah, Wh7, accA);
      accA = mfma_(ah, Wl7, accA);
      accA = mfma_(al, Wh7, accA);
    }
    if (g != 0) {
      #pragma unroll
      for (int r = 0; r < 4; r++) gbuf[0][hm][g - 1][4 * q + r][c] = accA[r];
    }
    __syncthreads();   // BA1

    if (g == 0) {
      _Float16 hvs[4], lvs[4];
      #pragma unroll
      for (int r = 0; r < 4; r++) {
        float gi = accA[r];
        float gf = gbuf[0][hm][0][4 * q + r][c];
        float gg = gbuf[0][hm][1][4 * q + r][c];
        float go = gbuf[0][hm][2][4 * q + r][c];
        float cn = sigf(gf) * cregA[r] + sigf(gi) * tanh_(gg);
        float hn = sigf(go) * tanh_(cn);
        cregA[r] = cn;
        hvs[r] = (_Float16)hn;
        lvs[r] = (_Float16)(hn - (float)hvs[r]);
        if (more) {
          unsigned int pk = (unsigned int)__builtin_bit_cast(unsigned short, hvs[r]) |
                            ((unsigned int)__builtin_bit_cast(unsigned short, lvs[r]) << 16);
          __hip_atomic_store(&g_hxs[t & 1][bgA][d][fb + (4 * q + r) * 8], pk,
                             __ATOMIC_RELAXED, __HIP_MEMORY_SCOPE_AGENT);
        }
      }
      if (more) {
        asm volatile("s_waitcnt vmcnt(0)" ::: "memory");
        if (lane == 0)
          __hip_atomic_store(&g_syncp[layer][bgA][d][s][hm][0], t + 1,
                             __ATOMIC_RELAXED, __HIP_MEMORY_SCOPE_AGENT);
      }
      #pragma unroll
      for (int r = 0; r < 4; r++) {
        int bi = bgA * 16 + 4 * q + r;
        int rv = (d == 0) ? bi * Tn + t : g_rev[bi * Tn + t];
        size_t fo = (size_t)rv * 512 + d * 256 + u;
        fh[fo] = hvs[r];
        fl[fo] = lvs[r];
      }
    }

    // ================= chain B compute (hides A's exchange RTT) =================
    f32x4 accB;
    #pragma unroll
    for (int r = 0; r < 4; r++) accB[r] = xgB[r];
    #pragma unroll
    for (int kc = 0; kc < 7; kc++) {
      f16x8 ah = *(const f16x8*)(lhB + (kc * 64 + lane) * 8);
      f16x8 al = *(const f16x8*)(llB + (kc * 64 + lane) * 8);
      f16x8 wh = *(const f16x8*)&Wh_l[w][kc][lane * 8];
      f16x8 wl = *(const f16x8*)&Wl_l[w][kc][lane * 8];
      accB = mfma_(ah, wh, accB);
      accB = mfma_(ah, wl, accB);
      accB = mfma_(al, wh, accB);
    }
    {
      f16x8 ah = *(const f16x8*)(lhB + (7 * 64 + lane) * 8);
      f16x8 al = *(const f16x8*)(llB + (7 * 64 + lane) * 8);
      accB = mfma_(ah, Wh7, accB);
      accB = mfma_(ah, Wl7, accB);
      accB = mfma_(al, Wh7, accB);
    }
    if (g != 0) {
      #pragma unroll
      for (int r = 0; r < 4; r++) gbuf[1][hm][g - 1][4 * q + r][c] = accB[r];
    }
    __syncthreads();   // BB1

    if (g == 0) {
      _Float16 hvs[4], lvs[4];
      #pragma unroll
      for (int r = 0; r < 4; r++) {
        float gi = accB[r];
        float gf = gbuf[1][hm][0][4 * q + r][c];
        float gg = gbuf[1][hm][1][4 * q + r][c];
        float go = gbuf[1][hm][2][4 * q + r][c];
        float cn = sigf(gf) * cregB[r] + sigf(gi) * tanh_(gg);
        float hn = sigf(go) * tanh_(cn);
        cregB[r] = cn;
        hvs[r] = (_Float16)hn;
        lvs[r] = (_Float16)(hn - (float)hvs[r]);
        if (more) {
          unsigned int pk = (unsigned int)__builtin_bit_cast(unsigned short, hvs[r]) |
                            ((unsigned int)__builtin_bit_cast(unsigned short, lvs[r]) << 16);
          __hip_atomic_store(&g_hxs[t & 1][bgB][d][fb + (4 * q + r) * 8], pk,
                             __ATOMIC_RELAXED, __HIP_MEMORY_SCOPE_AGENT);
        }
      }
      if (more) {
        asm volatile("s_waitcnt vmcnt(0)" ::: "memory");
        if (lane == 0)
          __hip_atomic_store(&g_syncp[layer][bgB][d][s][hm][0], t + 1,
                             __ATOMIC_RELAXED, __HIP_MEMORY_SCOPE_AGENT);
      }
      #pragma unroll
      for (int r = 0; r < 4; r++) {
        int bi = bgB * 16 + 4 * q + r;
        int rv = (d == 0) ? bi * Tn + t : g_rev[bi * Tn + t];
        size_t fo = (size_t)rv * 512 + d * 256 + u;
        fh[fo] = hvs[r];
        fl[fo] = lvs[r];
      }
    }

    if (more) {
      // xg prefetch for t+1 (both chains) — flies under the polls
      float xnA[4], xnB[4];
      #pragma unroll
      for (int r = 0; r < 4; r++) {
        xnA[r] = g_xg[xoffA[r] + (size_t)(t + 1) * 2048 + col];
        xnB[r] = g_xg[xoffB[r] + (size_t)(t + 1) * 2048 + col];
      }

      // 32 pollers in wave 7: lanes 0-15 chain A flags, lanes 16-31 chain B flags
      if (w == 7 && lane < 32) {
        const int li = lane & 15;
        const int bgp = (lane < 16) ? bgA : bgB;
        const int* fp = &g_syncp[layer][bgp][d][li >> 1][li & 1][0];
        while (__hip_atomic_load(fp, __ATOMIC_RELAXED, __HIP_MEMORY_SCOPE_AGENT) < t + 1)
          __builtin_amdgcn_s_sleep(1);
      }
      __syncthreads();   // B3: all 32 half-flags observed

      // single-RTT read of both staged chunks: 8 concurrent u64 loads
      const unsigned long long* sA = (const unsigned long long*)&g_hxs[t & 1][bgA][d][0];
      const unsigned long long* sB = (const unsigned long long*)&g_hxs[t & 1][bgB][d][0];
      unsigned long long p0 = __hip_atomic_load(sA + tid * 4 + 0, __ATOMIC_RELAXED,
                                                __HIP_MEMORY_SCOPE_AGENT);
      unsigned long long p1 = __hip_atomic_load(sA + tid * 4 + 1, __ATOMIC_RELAXED,
                                                __HIP_MEMORY_SCOPE_AGENT);
      unsigned long long p2 = __hip_atomic_load(sA + tid * 4 + 2, __ATOMIC_RELAXED,
                                                __HIP_MEMORY_SCOPE_AGENT);
      unsigned long long p3 = __hip_atomic_load(sA + tid * 4 + 3, __ATOMIC_RELAXED,
                                                __HIP_MEMORY_SCOPE_AGENT);
      unsigned long long r0 = __hip_atomic_load(sB + tid * 4 + 0, __ATOMIC_RELAXED,
                                                __HIP_MEMORY_SCOPE_AGENT);
      unsigned long long r1 = __hip_atomic_load(sB + tid * 4 + 1, __ATOMIC_RELAXED,
                                                __HIP_MEMORY_SCOPE_AGENT);
      unsigned long long r2 = __hip_atomic_load(sB + tid * 4 + 2, __ATOMIC_RELAXED,
                                                __HIP_MEMORY_SCOPE_AGENT);
      unsigned long long r3 = __hip_atomic_load(sB + tid * 4 + 3, __ATOMIC_RELAXED,
                                                __HIP_MEMORY_SCOPE_AGENT);
      {
        unsigned int w0 = (unsigned int)p0, w1 = (unsigned int)(p0 >> 32);
        unsigned int w2 = (unsigned int)p1, w3 = (unsigned int)(p1 >> 32);
        unsigned int w4 = (unsigned int)p2, w5 = (unsigned int)(p2 >> 32);
        unsigned int w6 = (unsigned int)p3, w7 = (unsigned int)(p3 >> 32);
        uint4 hiw, low;
        hiw.x = (w0 & 0xffffu) | (w1 << 16);
        hiw.y = (w2 & 0xffffu) | (w3 << 16);
        hiw.z = (w4 & 0xffffu) | (w5 << 16);
        hiw.w = (w6 & 0xffffu) | (w7 << 16);
        low.x = (w0 >> 16) | (w1 & 0xffff0000u);
        low.y = (w2 >> 16) | (w3 & 0xffff0000u);
        low.z = (w4 >> 16) | (w5 & 0xffff0000u);
        low.w = (w6 >> 16) | (w7 & 0xffff0000u);
        *(uint4*)&lhA[tid * 8] = hiw;
        *(uint4*)&llA[tid * 8] = low;
      }
      {
        unsigned int w0 = (unsigned int)r0, w1 = (unsigned int)(r0 >> 32);
        unsigned int w2 = (unsigned int)r1, w3 = (unsigned int)(r1 >> 32);
        unsigned int w4 = (unsigned int)r2, w5 = (unsigned int)(r2 >> 32);
        unsigned int w6 = (unsigned int)r3, w7 = (unsigned int)(r3 >> 32);
        uint4 hiw, low;
        hiw.x = (w0 & 0xffffu) | (w1 << 16);
        hiw.y = (w2 & 0xffffu) | (w3 << 16);
        hiw.z = (w4 & 0xffffu) | (w5 << 16);
        hiw.w = (w6 & 0xffffu) | (w7 << 16);
        low.x = (w0 >> 16) | (w1 & 0xffff0000u);
        low.y = (w2 >> 16) | (w3 & 0xffff0000u);
        low.z = (w4 >> 16) | (w5 & 0xffff0000u);
        low.w = (w6 >> 16) | (w7 & 0xffff0000u);
        *(uint4*)&lhB[tid * 8] = hiw;
        *(uint4*)&llB[tid * 8] = low;
      }
      __syncthreads();   // B4: new h visible wg-wide (both chains)
      #pragma unroll
      for (int r = 0; r < 4; r++) {
        xgA[r] = xnA[r];
        xgB[r] = xnB[r];
      }
    }
  }
}

// ---------------- CRF alpha scan + Viterbi forward (8-step em prefetch) ----------------
__global__ __launch_bounds__(64) void k_scan(const int* __restrict__ lengths,
                                             const int* __restrict__ y_true,
                                             const float* __restrict__ start,
                                             const float* __restrict__ endt,
                                             const float* __restrict__ trans) {
  const int b = blockIdx.x, j = threadIdx.x;
  const int V = lengths[b] * 4;
  const float* em = g_em + (size_t)b * (Tn * 44);
  float tcol[11];
  #pragma unroll
  for (int i = 0; i < 11; i++) tcol[i] = (j < 11) ? trans[i * 11 + j] : 0.f;
  float alpha = (j < 11) ? start[j] + em[j] : -1e30f;
  float score = alpha;
  for (int s0 = 1; s0 < V; s0 += 8) {
    float eb[8];
    #pragma unroll
    for (int k = 0; k < 8; k++) {
      int s = s0 + k;
      eb[k] = (j < 11 && s < Sn) ? em[s * 11 + j] : 0.f;
    }
    #pragma unroll
    for (int k = 0; k < 8; k++) {
      int s = s0 + k;
      if (s < V) {
        float e = eb[k];
        float av[11];
        float m = -1e30f, bestv = -1e30f;
        int bi = 0;
        #pragma unroll
        for (int i = 0; i < 11; i++) {
          float ai = __shfl(alpha, i);
          float si = __shfl(score, i);
          float va = ai + tcol[i];
          float vs = si + tcol[i];
          av[i] = va;
          m = fmaxf(m, va);
          if (vs > bestv) { bestv = vs; bi = i; }  // first-wins argmax
        }
        float sum = 0.f;
        #pragma unroll
        for (int i = 0; i < 11; i++) sum += __expf(av[i] - m);
        alpha = e + m + __logf(sum);
        score = bestv + e;
        if (j < 11) g_hist[(size_t)s * (Bn * NTn) + b * NTn + j] = (unsigned char)bi;
      }
    }
  }
  float ae = (j < 11) ? alpha + endt[j] : -1e30f;
  float se = (j < 11) ? score + endt[j] : -1e30f;
  float m2 = -1e30f;
  #pragma unroll
  for (int i = 0; i < 11; i++) m2 = fmaxf(m2, __shfl(ae, i));
  float s2 = 0.f;
  #pragma unroll
  for (int i = 0; i < 11; i++) s2 += __expf(__shfl(ae, i) - m2);
  float logZ = m2 + __logf(s2);
  float bv = -1e30f;
  int bj = 0;
  #pragma unroll
  for (int i = 0; i < 11; i++) {
    float v = __shfl(se, i);
    if (v > bv) { bv = v; bj = i; }
  }
  const int* y = y_true + (size_t)b * Sn;
  float part = 0.f;
  for (int s = 1 + j; s < V; s += 64) {
    int yp = y[s - 1], yc = y[s];
    part += trans[yp * 11 + yc] + em[s * 11 + yc];
  }
  #pragma unroll
  for (int off = 32; off > 0; off >>= 1) part += __shfl_down(part, off);
  if (j == 0) {
    int y0 = y[0];
    float num = start[y0] + em[y0] + part + endt[y[V - 1]];
    g_llh[b] = num - logZ;
    g_last[b] = bj;
  }
}

// ---------------- Viterbi backtrace (double-buffered) + loss reduce ----------------
__global__ __launch_bounds__(256) void k_back(const int* __restrict__ lengths,
                                              float* __restrict__ out) {
  __shared__ unsigned char hbuf[2][64 * Bn * NTn];  // 2 x 45056 B
  const int tid = threadIdx.x;
  if (tid == 0) {
    float ssum = 0.f;
    for (int b = 0; b < Bn; b++) ssum += g_llh[b];
    out[0] = -ssum / (float)Bn;
  }
  int carry = 0, V = 0;
  if (tid < 64) {
    carry = g_last[tid];
    V = lengths[tid] * 4;
    out[1 + (size_t)tid * Sn + (Sn - 1)] = (float)carry;
  }
  constexpr int CHW = 64 * Bn * NTn / 4;   // dwords per chunk
  const int nc = Sn / 64;                   // 64 chunks
  {
    const unsigned int* src =
        (const unsigned int*)(g_hist + (size_t)(nc - 1) * 64 * (Bn * NTn));
    unsigned int* dst = (unsigned int*)hbuf[(nc - 1) & 1];
    for (int i = tid; i < CHW; i += 256) dst[i] = src[i];
  }
  __syncthreads();
  for (int c = nc - 1; c >= 0; c--) {
    if (c > 0 && tid >= 64) {   // threads 64..255 prefetch chunk c-1
      const unsigned int* src =
          (const unsigned int*)(g_hist + (size_t)(c - 1) * 64 * (Bn * NTn));
      unsigned int* dst = (unsigned int*)hbuf[(c - 1) & 1];
      for (int i = tid - 64; i < CHW; i += 192) dst[i] = src[i];
    }
    if (tid < 64) {             // lanes 0..63 backtrace chunk c
      const unsigned char* hb = hbuf[c & 1];
      const int s0 = c * 64;
      for (int s = s0 + 63; s >= s0 && s >= 1; s--) {
        int pr = hb[(s - s0) * (Bn * NTn) + tid * NTn + carry];
        if (s < V) carry = pr;
        out[1 + (size_t)tid * Sn + (s - 1)] = (float)carry;
      }
    }
    __syncthreads();
  }
}

// ---------------- host ----------------
extern "C" void kernel_launch(void* const* d_in, const int* in_sizes, int n_in,
                              void* d_out, int out_size, void* d_ws, size_t ws_size,
                              hipStream_t stream) {
  (void)in_sizes; (void)n_in; (void)d_ws; (void)ws_size; (void)out_size;
  const float* x        = (const float*)d_in[0];
  const int*   y_true   = (const int*)d_in[1];
  const int*   lengths  = (const int*)d_in[2];
  const float* h0       = (const float*)d_in[3];
  const float* c0       = (const float*)d_in[4];
  const float* w_ih_l0  = (const float*)d_in[5];
  const float* w_hh_l0  = (const float*)d_in[6];
  const float* b_l0     = (const float*)d_in[7];
  const float* w_ih_l0r = (const float*)d_in[8];
  const float* w_hh_l0r = (const float*)d_in[9];
  const float* b_l0r    = (const float*)d_in[10];
  const float* w_ih_l1  = (const float*)d_in[11];
  const float* w_hh_l1  = (const float*)d_in[12];
  const float* b_l1     = (const float*)d_in[13];
  const float* w_ih_l1r = (const float*)d_in[14];
  const float* w_hh_l1r = (const float*)d_in[15];
  const float* b_l1r    = (const float*)d_in[16];
  const float* w_out    = (const float*)d_in[17];
  const float* b_out    = (const float*)d_in[18];
  const float* start_t  = (const float*)d_in[19];
  const float* end_t    = (const float*)d_in[20];
  const float* trans    = (const float*)d_in[21];
  float* out = (float*)d_out;

  auto gs = [](int n) { return dim3((n + 255) / 256); };
  dim3 b256(256);

  // weight prep + sync-flag reset (runs every call for graph-replay determinism)
  k_zinit<<<gs(4096), b256, 0, stream>>>();
  k_wswz<<<gs(4 * Gn * Hn), b256, 0, stream>>>(w_hh_l0, w_hh_l0r, w_hh_l1, w_hh_l1r);
  k_split<<<gs(131072), b256, 0, stream>>>(w_ih_l0, 1, 0, 131072);
  k_split<<<gs(131072), b256, 0, stream>>>(w_ih_l0r, 1, 131072, 131072);
  k_split<<<gs(524288), b256, 0, stream>>>(w_ih_l1, 2, 0, 524288);
  k_split<<<gs(524288), b256, 0, stream>>>(w_ih_l1r, 2, 524288, 524288);
  k_split<<<gs(22528), b256, 0, stream>>>(w_out, 3, 0, 22528);
  k_copy<<<gs(1024), b256, 0, stream>>>(b_l0, 0, 0, 1024);
  k_copy<<<gs(1024), b256, 0, stream>>>(b_l0r, 0, 1024, 1024);
  k_copy<<<gs(1024), b256, 0, stream>>>(b_l1, 1, 0, 1024);
  k_copy<<<gs(1024), b256, 0, stream>>>(b_l1r, 1, 1024, 1024);
  k_copy<<<gs(44), b256, 0, stream>>>(b_out, 2, 0, 44);
  k_pad<<<gs(2048), b256, 0, stream>>>();
  k_rev<<<gs(BT), b256, 0, stream>>>(lengths);
  k_xpose<<<dim3(Tn / 32, Fn / 32, Bn), dim3(32, 8), 0, stream>>>(x);

  // layer 0
  k_gemm<0, 3><<<dim3(BT / 128, 16), b256, 0, stream>>>();
  k_rec5<<<dim3(2, 2, 8), dim3(512), 0, stream>>>(h0, c0, 0);
  // layer 1
  k_gemm<1, 3><<<dim3(BT / 128, 16), b256, 0, stream>>>();
  k_rec5<<<dim3(2, 2, 8), dim3(512), 0, stream>>>(h0, c0, 1);
  // emissions
  k_gemm<2, 3><<<dim3(BT / 128, 1), b256, 0, stream>>>();
  // CRF + viterbi
  k_scan<<<dim3(Bn), dim3(64), 0, stream>>>(lengths, y_true, start_t, end_t, trans);
  k_back<<<dim3(1), b256, 0, stream>>>(lengths, out);
}

// Round 17
// 12145.643 us; speedup vs baseline: 1.4976x; 1.4976x over previous
//
#include <hip/hip_runtime.h>
#include <hip/hip_bf16.h>

typedef _Float16 f16x8 __attribute__((ext_vector_type(8)));
typedef float f32x4 __attribute__((ext_vector_type(4)));

#define DI static __device__ __forceinline__

constexpr int Bn = 64, Fn = 128, Tn = 1024, Hn = 256, NTn = 11;
constexpr int BT = Bn * Tn;       // 65536
constexpr int Gn = 4 * Hn;        // 1024
constexpr int Sn = 4 * Tn;        // 4096

// ---------------- device global buffers (no d_ws use) ----------------
__device__ __align__(16) _Float16 g_xt_h[BT * Fn];
__device__ __align__(16) _Float16 g_xt_l[BT * Fn];
__device__ __align__(16) _Float16 g_f0_h[BT * 512];
__device__ __align__(16) _Float16 g_f0_l[BT * 512];
__device__ __align__(16) _Float16 g_f1_h[BT * 512];
__device__ __align__(16) _Float16 g_f1_l[BT * 512];
__device__ __align__(16) float    g_xg[(size_t)BT * 2048];   // 512MB, reused per layer
__device__ __align__(16) _Float16 g_whh_h[4 * Gn * Hn];      // fragment-swizzled
__device__ __align__(16) _Float16 g_whh_l[4 * Gn * Hn];
__device__ __align__(16) _Float16 g_wih0_h[2048 * Fn];
__device__ __align__(16) _Float16 g_wih0_l[2048 * Fn];
__device__ __align__(16) _Float16 g_wih1_h[2048 * 512];
__device__ __align__(16) _Float16 g_wih1_l[2048 * 512];
__device__ __align__(16) _Float16 g_wout_h[48 * 512];
__device__ __align__(16) _Float16 g_wout_l[48 * 512];
__device__ float g_b0[2048], g_b1[2048], g_bo[48];
__device__ float g_em[BT * 44];
__device__ __align__(4) unsigned char g_hist[(size_t)Sn * Bn * NTn];
__device__ int   g_rev[BT];
__device__ float g_llh[Bn];
__device__ int   g_last[Bn];
// cross-wg h staging, producer-contiguous layout:
// slot = s*512 + hm*256 + lane*4 + r  holds (h_hi | h_lo<<16) for
// unit u = (2s+hm)*16 + (lane&15), row = 4*(lane>>4) + r
__device__ __align__(16) unsigned int g_hxs[2][4][2][4096];
// per-producer half-flags: [layer][bg][d][prod][hm][16 ints pad = 64B/flag]
__device__ int g_syncp[2][4][2][8][2][16];

DI f32x4 mfma_(f16x8 a, f16x8 b, f32x4 c) {
  return __builtin_amdgcn_mfma_f32_16x16x32_f16(a, b, c, 0, 0, 0);
}
DI float sigf(float x) { return 1.f / (1.f + __expf(-x)); }
DI float tanh_(float x) { return 1.f - 2.f / (1.f + __expf(2.f * x)); }

// ---------------- prep kernels ----------------
__global__ void k_zinit() {
  int i = blockIdx.x * 256 + threadIdx.x;
  if (i < 2 * 4 * 2 * 8 * 2 * 16) ((int*)g_syncp)[i] = 0;
}

__global__ void k_split(const float* __restrict__ src, int which, int off, int n) {
  int i = blockIdx.x * 256 + threadIdx.x;
  if (i >= n) return;
  float v = src[i];
  _Float16 h = (_Float16)v;
  _Float16 l = (_Float16)(v - (float)h);
  _Float16 *H, *L;
  switch (which) {
    case 1:  H = g_wih0_h; L = g_wih0_l; break;
    case 2:  H = g_wih1_h; L = g_wih1_l; break;
    default: H = g_wout_h; L = g_wout_l; break;
  }
  H[off + i] = h; L[off + i] = l;
}

// W_hh -> fragment-contiguous swizzle: idx = (((nt*8 + kc)*64 + lane)*8 + j)
// holds W[nt*16 + (lane&15)][kc*32 + (lane>>4)*8 + j]
__global__ void k_wswz(const float* __restrict__ w0, const float* __restrict__ w1,
                       const float* __restrict__ w2, const float* __restrict__ w3) {
  int i = blockIdx.x * 256 + threadIdx.x;
  if (i >= 4 * Gn * Hn) return;
  int mat = i >> 18;
  int e = i & 262143;
  int nt = e >> 12, rem = e & 4095;
  int kc = rem >> 9;
  int rem2 = rem & 511;
  int lane = rem2 >> 3, j = rem2 & 7;
  int row = nt * 16 + (lane & 15);
  int col = kc * 32 + (lane >> 4) * 8 + j;
  const float* src = mat == 0 ? w0 : mat == 1 ? w1 : mat == 2 ? w2 : w3;
  float v = src[row * Hn + col];
  _Float16 h = (_Float16)v;
  g_whh_h[i] = h;
  g_whh_l[i] = (_Float16)(v - (float)h);
}

__global__ void k_copy(const float* __restrict__ src, int which, int off, int n) {
  int i = blockIdx.x * 256 + threadIdx.x;
  if (i >= n) return;
  float* D = which == 0 ? g_b0 : which == 1 ? g_b1 : g_bo;
  D[off + i] = src[i];
}

__global__ void k_pad() {
  int i = blockIdx.x * 256 + threadIdx.x;
  if (i < 48 * 512 - 44 * 512) {            // zero pad rows 44..47 of w_out
    g_wout_h[44 * 512 + i] = (_Float16)0.f;
    g_wout_l[44 * 512 + i] = (_Float16)0.f;
  }
  if (i < 4) g_bo[44 + i] = 0.f;
}

__global__ void k_rev(const int* __restrict__ lengths) {
  int i = blockIdx.x * 256 + threadIdx.x;
  if (i >= BT) return;
  int b = i >> 10, t = i & 1023;
  int len = lengths[b];
  int r = (t < len) ? (len - 1 - t) : t;
  g_rev[i] = (b << 10) | r;
}

// x (B,F,T) -> xt rows (b*T+t, d) split to f16 hi/lo
__global__ void k_xpose(const float* __restrict__ x) {
  __shared__ float tile[32][33];
  int t0 = blockIdx.x * 32, d0 = blockIdx.y * 32, b = blockIdx.z;
  int tx = threadIdx.x, ty = threadIdx.y;
  #pragma unroll
  for (int i = 0; i < 4; i++) {
    int d = d0 + ty + i * 8;
    tile[ty + i * 8][tx] = x[((size_t)b * Fn + d) * Tn + t0 + tx];
  }
  __syncthreads();
  #pragma unroll
  for (int i = 0; i < 4; i++) {
    int t = t0 + ty + i * 8;
    float v = tile[tx][ty + i * 8];
    _Float16 h = (_Float16)v;
    size_t o = ((size_t)b * Tn + t) * Fn + d0 + tx;
    g_xt_h[o] = h;
    g_xt_l[o] = (_Float16)(v - (float)h);
  }
}

// ---------------- generic dual-f16 MFMA GEMM ----------------
// SEL: 0 = proj layer0 (A=xt,K=128), 1 = proj layer1 (A=f0,K=512), 2 = emissions (A=f1,N=48->44)
template <int SEL, int NPL>
__global__ __launch_bounds__(256) void k_gemm() {
  constexpr int KD = SEL == 0 ? 128 : 512;
  constexpr int WM = SEL == 2 ? 4 : 2;
  constexpr int WN = SEL == 2 ? 1 : 2;
  constexpr int MW = SEL == 2 ? 2 : 4;
  constexpr int NW = SEL == 2 ? 3 : 4;
  constexpr int LDO = SEL == 2 ? 44 : 2048;
  constexpr int NCOL = SEL == 2 ? 44 : 2048;
  constexpr int NSPLIT = SEL == 2 ? (1 << 30) : 1024;
  const _Float16* Ah = SEL == 0 ? g_xt_h : SEL == 1 ? g_f0_h : g_f1_h;
  const _Float16* Al = SEL == 0 ? g_xt_l : SEL == 1 ? g_f0_l : g_f1_l;
  const _Float16* Bh = SEL == 0 ? g_wih0_h : SEL == 1 ? g_wih1_h : g_wout_h;
  const _Float16* Bl = SEL == 0 ? g_wih0_l : SEL == 1 ? g_wih1_l : g_wout_l;
  const float* bias = SEL == 0 ? g_b0 : SEL == 1 ? g_b1 : g_bo;
  float* out = SEL == 2 ? g_em : g_xg;

  const int lane = threadIdx.x & 63, wv = threadIdx.x >> 6;
  const int wm = wv / WN, wn = wv % WN;
  const int c = lane & 15, q = lane >> 4;
  const int bm0 = blockIdx.x * (WM * MW * 16);
  const int bn0 = blockIdx.y * (WN * NW * 16);
  const bool bw = bn0 >= NSPLIT;   // backward-direction column block -> gathered A rows
  int arow[MW];
  #pragma unroll
  for (int mi = 0; mi < MW; mi++) {
    int r = bm0 + (wm * MW + mi) * 16 + c;
    arow[mi] = bw ? g_rev[r] : r;
  }
  f32x4 acc[MW][NW];
  #pragma unroll
  for (int mi = 0; mi < MW; mi++)
    #pragma unroll
    for (int ni = 0; ni < NW; ni++) acc[mi][ni] = f32x4{0.f, 0.f, 0.f, 0.f};

  for (int kc = 0; kc < KD / 32; kc++) {
    const int k = kc * 32 + q * 8;
    f16x8 ah[MW], al[MW], bh[NW], bl[NW];
    #pragma unroll
    for (int mi = 0; mi < MW; mi++) {
      ah[mi] = *(const f16x8*)(Ah + (size_t)arow[mi] * KD + k);
      if constexpr (NPL > 1) al[mi] = *(const f16x8*)(Al + (size_t)arow[mi] * KD + k);
    }
    #pragma unroll
    for (int ni = 0; ni < NW; ni++) {
      int n = bn0 + (wn * NW + ni) * 16 + c;
      bh[ni] = *(const f16x8*)(Bh + (size_t)n * KD + k);
      if constexpr (NPL > 1) bl[ni] = *(const f16x8*)(Bl + (size_t)n * KD + k);
    }
    #pragma unroll
    for (int mi = 0; mi < MW; mi++)
      #pragma unroll
      for (int ni = 0; ni < NW; ni++) {
        acc[mi][ni] = mfma_(ah[mi], bh[ni], acc[mi][ni]);
        if constexpr (NPL > 1) {
          acc[mi][ni] = mfma_(ah[mi], bl[ni], acc[mi][ni]);
          acc[mi][ni] = mfma_(al[mi], bh[ni], acc[mi][ni]);
        }
      }
  }
  #pragma unroll
  for (int mi = 0; mi < MW; mi++)
    #pragma unroll
    for (int ni = 0; ni < NW; ni++) {
      int col = bn0 + (wn * NW + ni) * 16 + c;
      if (col < NCOL) {
        int row0 = bm0 + (wm * MW + mi) * 16 + q * 4;
        float bv = bias[col];
        #pragma unroll
        for (int r = 0; r < 4; r++)
          out[(size_t)(row0 + r) * LDO + col] = acc[mi][ni][r] + bv;
      }
    }
}

// ---------------- LSTM recurrence: oct of 8 wgs per (bg,dir), W_hh in LDS ----------------
// Round-14 structure with producer-contiguous staging: each g==0 thread's 4 staged
// values are contiguous -> TWO 8B LLC-serviced atomic stores (2 concurrent acks to
// drain before the flag post, was 4 separate dword acks). Consumers read 8
// stride-16B dword atomic loads (1 RTT, same unpack). Flags/barriers identical.
__global__ __launch_bounds__(512, 1) void k_rec3(const float* __restrict__ h0,
                                                 const float* __restrict__ c0, int layer) {
  __shared__ __align__(16) _Float16 Wh_l[8][8][512];      // 64 KB
  __shared__ __align__(16) _Float16 Wl_l[8][8][512];      // 64 KB
  __shared__ __align__(16) _Float16 lh[4096], ll[4096];   // 16 KB
  __shared__ float gbuf[2][3][16][16];                    // 6 KB
  const int tid = threadIdx.x, lane = tid & 63, w = tid >> 6;  // 8 waves
  const int c = lane & 15, q = lane >> 4;
  const int bg = blockIdx.x, d = blockIdx.y, s = blockIdx.z;
  const int dirIdx = layer * 2 + d;
  const int g = w >> 1, hm = w & 1;
  const int m = 2 * s + hm;            // unit-tile 0..15
  const int nt = g * 16 + m;           // gate tile 0..63
  const int u = m * 16 + c;            // global unit 0..255
  const _Float16* whp = g_whh_h + (size_t)dirIdx * (Gn * Hn);
  const _Float16* wlp = g_whh_l + (size_t)dirIdx * (Gn * Hn);
  _Float16* fh = layer ? g_f1_h : g_f0_h;
  _Float16* fl = layer ? g_f1_l : g_f0_l;
  const float* h0p = h0 + ((size_t)dirIdx * Bn + bg * 16) * Hn;
  const float* c0p = c0 + ((size_t)dirIdx * Bn + bg * 16) * Hn;

  // W slice -> LDS (once)
  #pragma unroll
  for (int kc = 0; kc < 8; kc++) {
    *(f16x8*)&Wh_l[w][kc][lane * 8] =
        *(const f16x8*)(whp + ((size_t)(nt * 8 + kc) * 64 + lane) * 8);
    *(f16x8*)&Wl_l[w][kc][lane * 8] =
        *(const f16x8*)(wlp + ((size_t)(nt * 8 + kc) * 64 + lane) * 8);
  }
  // h0 -> fragment LDS
  for (int i = tid; i < 4096; i += 512) {
    int j = i & 7, ln = (i >> 3) & 63, kc = i >> 9;
    int row = ln & 15, uu = kc * 32 + ((ln >> 4) * 8) + j;
    float v = h0p[row * Hn + uu];
    _Float16 hv = (_Float16)v;
    lh[i] = hv;
    ll[i] = (_Float16)(v - (float)hv);
  }
  float creg[4];
  if (g == 0) {
    #pragma unroll
    for (int r = 0; r < 4; r++) creg[r] = c0p[(4 * q + r) * Hn + u];
  }
  // xg addressing: col = d*1024 + g*256 + u
  size_t xoff[4];
  #pragma unroll
  for (int r = 0; r < 4; r++)
    xoff[r] = ((size_t)(bg * 16 + 4 * q + r) * Tn) * 2048 + (size_t)d * 1024;
  const int col = g * 256 + u;
  // consumer read base: tid = kc*64 + qq*16 + row reads slots cbase + 4j, j=0..7
  const int ckc = tid >> 6, cqq = (tid >> 4) & 3, crow = tid & 15;
  const int cbase = ckc * 512 + (cqq >> 1) * 256 +
                    (((crow >> 2) * 16 + (cqq & 1) * 8) << 2) + (crow & 3);

  float xgv[4];
  #pragma unroll
  for (int r = 0; r < 4; r++) xgv[r] = g_xg[xoff[r] + col];
  __syncthreads();

  for (int t = 0; t < Tn; t++) {
    f32x4 acc;
    #pragma unroll
    for (int r = 0; r < 4; r++) acc[r] = xgv[r];

    #pragma unroll
    for (int kc = 0; kc < 8; kc++) {
      f16x8 ah = *(const f16x8*)(lh + (kc * 64 + lane) * 8);
      f16x8 al = *(const f16x8*)(ll + (kc * 64 + lane) * 8);
      f16x8 wh = *(const f16x8*)&Wh_l[w][kc][lane * 8];
      f16x8 wl = *(const f16x8*)&Wl_l[w][kc][lane * 8];
      acc = mfma_(ah, wh, acc);
      acc = mfma_(ah, wl, acc);
      acc = mfma_(al, wh, acc);
    }

    if (g != 0) {
      #pragma unroll
      for (int r = 0; r < 4; r++) gbuf[hm][g - 1][4 * q + r][c] = acc[r];
    }
    __syncthreads();   // B1: gbuf ready; all LDS reads of lh/ll done

    const bool more = (t + 1 < Tn);
    if (g == 0) {
      _Float16 hvs[4], lvs[4];
      unsigned int pkw[4];
      #pragma unroll
      for (int r = 0; r < 4; r++) {
        float gi = acc[r];
        float gf = gbuf[hm][0][4 * q + r][c];
        float gg = gbuf[hm][1][4 * q + r][c];
        float go = gbuf[hm][2][4 * q + r][c];
        float cn = sigf(gf) * creg[r] + sigf(gi) * tanh_(gg);
        float hn = sigf(go) * tanh_(cn);
        creg[r] = cn;
        hvs[r] = (_Float16)hn;
        lvs[r] = (_Float16)(hn - (float)hvs[r]);
        pkw[r] = (unsigned int)__builtin_bit_cast(unsigned short, hvs[r]) |
                 ((unsigned int)__builtin_bit_cast(unsigned short, lvs[r]) << 16);
      }
      if (more) {
        // TWO contiguous 8B LLC-serviced stores (concurrent acks; ~1 RTT drain)
        unsigned long long* dst = (unsigned long long*)
            &g_hxs[t & 1][bg][d][s * 512 + hm * 256 + lane * 4];
        unsigned long long q0 = (unsigned long long)pkw[0] |
                                ((unsigned long long)pkw[1] << 32);
        unsigned long long q1 = (unsigned long long)pkw[2] |
                                ((unsigned long long)pkw[3] << 32);
        __hip_atomic_store(dst + 0, q0, __ATOMIC_RELAXED, __HIP_MEMORY_SCOPE_AGENT);
        __hip_atomic_store(dst + 1, q1, __ATOMIC_RELAXED, __HIP_MEMORY_SCOPE_AGENT);
        // wave-local drain: both staging stores acked at LLC before the flag
        asm volatile("s_waitcnt vmcnt(0)" ::: "memory");
        if (lane == 0)
          __hip_atomic_store(&g_syncp[layer][bg][d][s][hm][0], t + 1,
                             __ATOMIC_RELAXED, __HIP_MEMORY_SCOPE_AGENT);
      }
      // scattered fh/fl HBM stores AFTER the flag post (off the critical path)
      #pragma unroll
      for (int r = 0; r < 4; r++) {
        int bi = bg * 16 + 4 * q + r;
        int rv = (d == 0) ? bi * Tn + t : g_rev[bi * Tn + t];
        size_t fo = (size_t)rv * 512 + d * 256 + u;
        fh[fo] = hvs[r];
        fl[fo] = lvs[r];
      }
    }

    if (more) {
      // xg prefetch for t+1 — flies under the flag wait
      float xn[4];
      #pragma unroll
      for (int r = 0; r < 4; r++)
        xn[r] = g_xg[xoff[r] + (size_t)(t + 1) * 2048 + col];

      // 16 pollers in wave 7 (idle after B1), one half-flag line each
      if (w == 7 && lane < 16) {
        const int* fp = &g_syncp[layer][bg][d][lane >> 1][lane & 1][0];
        while (__hip_atomic_load(fp, __ATOMIC_RELAXED, __HIP_MEMORY_SCOPE_AGENT) < t + 1)
          __builtin_amdgcn_s_sleep(1);
      }
      __syncthreads();   // B3: all producers' flags observed

      // 8 concurrent stride-16B dword loads (1 RTT) + in-register unpack
      const unsigned int* sp = &g_hxs[t & 1][bg][d][0];
      unsigned int w0 = __hip_atomic_load(sp + cbase + 0,  __ATOMIC_RELAXED, __HIP_MEMORY_SCOPE_AGENT);
      unsigned int w1 = __hip_atomic_load(sp + cbase + 4,  __ATOMIC_RELAXED, __HIP_MEMORY_SCOPE_AGENT);
      unsigned int w2 = __hip_atomic_load(sp + cbase + 8,  __ATOMIC_RELAXED, __HIP_MEMORY_SCOPE_AGENT);
      unsigned int w3 = __hip_atomic_load(sp + cbase + 12, __ATOMIC_RELAXED, __HIP_MEMORY_SCOPE_AGENT);
      unsigned int w4 = __hip_atomic_load(sp + cbase + 16, __ATOMIC_RELAXED, __HIP_MEMORY_SCOPE_AGENT);
      unsigned int w5 = __hip_atomic_load(sp + cbase + 20, __ATOMIC_RELAXED, __HIP_MEMORY_SCOPE_AGENT);
      unsigned int w6 = __hip_atomic_load(sp + cbase + 24, __ATOMIC_RELAXED, __HIP_MEMORY_SCOPE_AGENT);
      unsigned int w7 = __hip_atomic_load(sp + cbase + 28, __ATOMIC_RELAXED, __HIP_MEMORY_SCOPE_AGENT);
      uint4 hiw, low;
      hiw.x = (w0 & 0xffffu) | (w1 << 16);
      hiw.y = (w2 & 0xffffu) | (w3 << 16);
      hiw.z = (w4 & 0xffffu) | (w5 << 16);
      hiw.w = (w6 & 0xffffu) | (w7 << 16);
      low.x = (w0 >> 16) | (w1 & 0xffff0000u);
      low.y = (w2 >> 16) | (w3 & 0xffff0000u);
      low.z = (w4 >> 16) | (w5 & 0xffff0000u);
      low.w = (w6 >> 16) | (w7 & 0xffff0000u);
      *(uint4*)&lh[tid * 8] = hiw;
      *(uint4*)&ll[tid * 8] = low;

      __syncthreads();   // B4: new h visible wg-wide
      #pragma unroll
      for (int r = 0; r < 4; r++) xgv[r] = xn[r];
    }
  }
}

// ---------------- CRF alpha scan + Viterbi forward (8-step em prefetch) ----------------
__global__ __launch_bounds__(64) void k_scan(const int* __restrict__ lengths,
                                             const int* __restrict__ y_true,
                                             const float* __restrict__ start,
                                             const float* __restrict__ endt,
                                             const float* __restrict__ trans) {
  const int b = blockIdx.x, j = threadIdx.x;
  const int V = lengths[b] * 4;
  const float* em = g_em + (size_t)b * (Tn * 44);
  float tcol[11];
  #pragma unroll
  for (int i = 0; i < 11; i++) tcol[i] = (j < 11) ? trans[i * 11 + j] : 0.f;
  float alpha = (j < 11) ? start[j] + em[j] : -1e30f;
  float score = alpha;
  for (int s0 = 1; s0 < V; s0 += 8) {
    float eb[8];
    #pragma unroll
    for (int k = 0; k < 8; k++) {
      int s = s0 + k;
      eb[k] = (j < 11 && s < Sn) ? em[s * 11 + j] : 0.f;
    }
    #pragma unroll
    for (int k = 0; k < 8; k++) {
      int s = s0 + k;
      if (s < V) {
        float e = eb[k];
        float av[11];
        float m = -1e30f, bestv = -1e30f;
        int bi = 0;
        #pragma unroll
        for (int i = 0; i < 11; i++) {
          float ai = __shfl(alpha, i);
          float si = __shfl(score, i);
          float va = ai + tcol[i];
          float vs = si + tcol[i];
          av[i] = va;
          m = fmaxf(m, va);
          if (vs > bestv) { bestv = vs; bi = i; }  // first-wins argmax
        }
        float sum = 0.f;
        #pragma unroll
        for (int i = 0; i < 11; i++) sum += __expf(av[i] - m);
        alpha = e + m + __logf(sum);
        score = bestv + e;
        if (j < 11) g_hist[(size_t)s * (Bn * NTn) + b * NTn + j] = (unsigned char)bi;
      }
    }
  }
  float ae = (j < 11) ? alpha + endt[j] : -1e30f;
  float se = (j < 11) ? score + endt[j] : -1e30f;
  float m2 = -1e30f;
  #pragma unroll
  for (int i = 0; i < 11; i++) m2 = fmaxf(m2, __shfl(ae, i));
  float s2 = 0.f;
  #pragma unroll
  for (int i = 0; i < 11; i++) s2 += __expf(__shfl(ae, i) - m2);
  float logZ = m2 + __logf(s2);
  float bv = -1e30f;
  int bj = 0;
  #pragma unroll
  for (int i = 0; i < 11; i++) {
    float v = __shfl(se, i);
    if (v > bv) { bv = v; bj = i; }
  }
  const int* y = y_true + (size_t)b * Sn;
  float part = 0.f;
  for (int s = 1 + j; s < V; s += 64) {
    int yp = y[s - 1], yc = y[s];
    part += trans[yp * 11 + yc] + em[s * 11 + yc];
  }
  #pragma unroll
  for (int off = 32; off > 0; off >>= 1) part += __shfl_down(part, off);
  if (j == 0) {
    int y0 = y[0];
    float num = start[y0] + em[y0] + part + endt[y[V - 1]];
    g_llh[b] = num - logZ;
    g_last[b] = bj;
  }
}

// ---------------- Viterbi backtrace (double-buffered) + loss reduce ----------------
__global__ __launch_bounds__(256) void k_back(const int* __restrict__ lengths,
                                              float* __restrict__ out) {
  __shared__ unsigned char hbuf[2][64 * Bn * NTn];  // 2 x 45056 B
  const int tid = threadIdx.x;
  if (tid == 0) {
    float ssum = 0.f;
    for (int b = 0; b < Bn; b++) ssum += g_llh[b];
    out[0] = -ssum / (float)Bn;
  }
  int carry = 0, V = 0;
  if (tid < 64) {
    carry = g_last[tid];
    V = lengths[tid] * 4;
    out[1 + (size_t)tid * Sn + (Sn - 1)] = (float)carry;
  }
  constexpr int CHW = 64 * Bn * NTn / 4;   // dwords per chunk
  const int nc = Sn / 64;                   // 64 chunks
  {
    const unsigned int* src =
        (const unsigned int*)(g_hist + (size_t)(nc - 1) * 64 * (Bn * NTn));
    unsigned int* dst = (unsigned int*)hbuf[(nc - 1) & 1];
    for (int i = tid; i < CHW; i += 256) dst[i] = src[i];
  }
  __syncthreads();
  for (int c = nc - 1; c >= 0; c--) {
    if (c > 0 && tid >= 64) {   // threads 64..255 prefetch chunk c-1
      const unsigned int* src =
          (const unsigned int*)(g_hist + (size_t)(c - 1) * 64 * (Bn * NTn));
      unsigned int* dst = (unsigned int*)hbuf[(c - 1) & 1];
      for (int i = tid - 64; i < CHW; i += 192) dst[i] = src[i];
    }
    if (tid < 64) {             // lanes 0..63 backtrace chunk c
      const unsigned char* hb = hbuf[c & 1];
      const int s0 = c * 64;
      for (int s = s0 + 63; s >= s0 && s >= 1; s--) {
        int pr = hb[(s - s0) * (Bn * NTn) + tid * NTn + carry];
        if (s < V) carry = pr;
        out[1 + (size_t)tid * Sn + (s - 1)] = (float)carry;
      }
    }
    __syncthreads();
  }
}

// ---------------- host ----------------
extern "C" void kernel_launch(void* const* d_in, const int* in_sizes, int n_in,
                              void* d_out, int out_size, void* d_ws, size_t ws_size,
                              hipStream_t stream) {
  (void)in_sizes; (void)n_in; (void)d_ws; (void)ws_size; (void)out_size;
  const float* x        = (const float*)d_in[0];
  const int*   y_true   = (const int*)d_in[1];
  const int*   lengths  = (const int*)d_in[2];
  const float* h0       = (const float*)d_in[3];
  const float* c0       = (const float*)d_in[4];
  const float* w_ih_l0  = (const float*)d_in[5];
  const float* w_hh_l0  = (const float*)d_in[6];
  const float* b_l0     = (const float*)d_in[7];
  const float* w_ih_l0r = (const float*)d_in[8];
  const float* w_hh_l0r = (const float*)d_in[9];
  const float* b_l0r    = (const float*)d_in[10];
  const float* w_ih_l1  = (const float*)d_in[11];
  const float* w_hh_l1  = (const float*)d_in[12];
  const float* b_l1     = (const float*)d_in[13];
  const float* w_ih_l1r = (const float*)d_in[14];
  const float* w_hh_l1r = (const float*)d_in[15];
  const float* b_l1r    = (const float*)d_in[16];
  const float* w_out    = (const float*)d_in[17];
  const float* b_out    = (const float*)d_in[18];
  const float* start_t  = (const float*)d_in[19];
  const float* end_t    = (const float*)d_in[20];
  const float* trans    = (const float*)d_in[21];
  float* out = (float*)d_out;

  auto gs = [](int n) { return dim3((n + 255) / 256); };
  dim3 b256(256);

  // weight prep + sync-flag reset (runs every call for graph-replay determinism)
  k_zinit<<<gs(4096), b256, 0, stream>>>();
  k_wswz<<<gs(4 * Gn * Hn), b256, 0, stream>>>(w_hh_l0, w_hh_l0r, w_hh_l1, w_hh_l1r);
  k_split<<<gs(131072), b256, 0, stream>>>(w_ih_l0, 1, 0, 131072);
  k_split<<<gs(131072), b256, 0, stream>>>(w_ih_l0r, 1, 131072, 131072);
  k_split<<<gs(524288), b256, 0, stream>>>(w_ih_l1, 2, 0, 524288);
  k_split<<<gs(524288), b256, 0, stream>>>(w_ih_l1r, 2, 524288, 524288);
  k_split<<<gs(22528), b256, 0, stream>>>(w_out, 3, 0, 22528);
  k_copy<<<gs(1024), b256, 0, stream>>>(b_l0, 0, 0, 1024);
  k_copy<<<gs(1024), b256, 0, stream>>>(b_l0r, 0, 1024, 1024);
  k_copy<<<gs(1024), b256, 0, stream>>>(b_l1, 1, 0, 1024);
  k_copy<<<gs(1024), b256, 0, stream>>>(b_l1r, 1, 1024, 1024);
  k_copy<<<gs(44), b256, 0, stream>>>(b_out, 2, 0, 44);
  k_pad<<<gs(2048), b256, 0, stream>>>();
  k_rev<<<gs(BT), b256, 0, stream>>>(lengths);
  k_xpose<<<dim3(Tn / 32, Fn / 32, Bn), dim3(32, 8), 0, stream>>>(x);

  // layer 0
  k_gemm<0, 3><<<dim3(BT / 128, 16), b256, 0, stream>>>();
  k_rec3<<<dim3(4, 2, 8), dim3(512), 0, stream>>>(h0, c0, 0);
  // layer 1
  k_gemm<1, 3><<<dim3(BT / 128, 16), b256, 0, stream>>>();
  k_rec3<<<dim3(4, 2, 8), dim3(512), 0, stream>>>(h0, c0, 1);
  // emissions
  k_gemm<2, 3><<<dim3(BT / 128, 1), b256, 0, stream>>>();
  // CRF + viterbi
  k_scan<<<dim3(Bn), dim3(64), 0, stream>>>(lengths, y_true, start_t, end_t, trans);
  k_back<<<dim3(1), b256, 0, stream>>>(lengths, out);
}

// Round 18
// 11457.507 us; speedup vs baseline: 1.5875x; 1.0601x over previous
//
#include <hip/hip_runtime.h>
#include <hip/hip_bf16.h>

typedef _Float16 f16x8 __attribute__((ext_vector_type(8)));
typedef float f32x4 __attribute__((ext_vector_type(4)));

#define DI static __device__ __forceinline__

constexpr int Bn = 64, Fn = 128, Tn = 1024, Hn = 256, NTn = 11;
constexpr int BT = Bn * Tn;       // 65536
constexpr int Gn = 4 * Hn;        // 1024
constexpr int Sn = 4 * Tn;        // 4096

// ---------------- device global buffers (no d_ws use) ----------------
__device__ __align__(16) _Float16 g_xt_h[BT * Fn];
__device__ __align__(16) _Float16 g_xt_l[BT * Fn];
__device__ __align__(16) _Float16 g_f0_h[BT * 512];
__device__ __align__(16) _Float16 g_f0_l[BT * 512];
__device__ __align__(16) _Float16 g_f1_h[BT * 512];
__device__ __align__(16) _Float16 g_f1_l[BT * 512];
__device__ __align__(16) float    g_xg[(size_t)BT * 2048];   // 512MB, reused per layer
__device__ __align__(16) _Float16 g_whh_h[4 * Gn * Hn];      // fragment-swizzled
__device__ __align__(16) _Float16 g_whh_l[4 * Gn * Hn];
__device__ __align__(16) _Float16 g_wih0_h[2048 * Fn];
__device__ __align__(16) _Float16 g_wih0_l[2048 * Fn];
__device__ __align__(16) _Float16 g_wih1_h[2048 * 512];
__device__ __align__(16) _Float16 g_wih1_l[2048 * 512];
__device__ __align__(16) _Float16 g_wout_h[48 * 512];
__device__ __align__(16) _Float16 g_wout_l[48 * 512];
__device__ float g_b0[2048], g_b1[2048], g_bo[48];
__device__ float g_em[BT * 44];
__device__ __align__(4) unsigned char g_hist[(size_t)Sn * Bn * NTn];
__device__ int   g_rev[BT];
__device__ float g_llh[Bn];
__device__ int   g_last[Bn];
// cross-wg h staging: [parity][bg][d][fragidx] packed (hi | lo<<16)
__device__ unsigned int g_hxs[2][4][2][4096];
// per-producer half-flags: [layer][bg][d][prod][hm][16 ints pad = 64B/flag]
__device__ int g_syncp[2][4][2][8][2][16];

DI f32x4 mfma_(f16x8 a, f16x8 b, f32x4 c) {
  return __builtin_amdgcn_mfma_f32_16x16x32_f16(a, b, c, 0, 0, 0);
}
DI float sigf(float x) { return 1.f / (1.f + __expf(-x)); }
DI float tanh_(float x) { return 1.f - 2.f / (1.f + __expf(2.f * x)); }

// ---------------- prep kernels ----------------
__global__ void k_zinit() {
  int i = blockIdx.x * 256 + threadIdx.x;
  if (i < 2 * 4 * 2 * 8 * 2 * 16) ((int*)g_syncp)[i] = 0;
}

__global__ void k_split(const float* __restrict__ src, int which, int off, int n) {
  int i = blockIdx.x * 256 + threadIdx.x;
  if (i >= n) return;
  float v = src[i];
  _Float16 h = (_Float16)v;
  _Float16 l = (_Float16)(v - (float)h);
  _Float16 *H, *L;
  switch (which) {
    case 1:  H = g_wih0_h; L = g_wih0_l; break;
    case 2:  H = g_wih1_h; L = g_wih1_l; break;
    default: H = g_wout_h; L = g_wout_l; break;
  }
  H[off + i] = h; L[off + i] = l;
}

// W_hh -> fragment-contiguous swizzle: idx = (((nt*8 + kc)*64 + lane)*8 + j)
// holds W[nt*16 + (lane&15)][kc*32 + (lane>>4)*8 + j]
__global__ void k_wswz(const float* __restrict__ w0, const float* __restrict__ w1,
                       const float* __restrict__ w2, const float* __restrict__ w3) {
  int i = blockIdx.x * 256 + threadIdx.x;
  if (i >= 4 * Gn * Hn) return;
  int mat = i >> 18;
  int e = i & 262143;
  int nt = e >> 12, rem = e & 4095;
  int kc = rem >> 9;
  int rem2 = rem & 511;
  int lane = rem2 >> 3, j = rem2 & 7;
  int row = nt * 16 + (lane & 15);
  int col = kc * 32 + (lane >> 4) * 8 + j;
  const float* src = mat == 0 ? w0 : mat == 1 ? w1 : mat == 2 ? w2 : w3;
  float v = src[row * Hn + col];
  _Float16 h = (_Float16)v;
  g_whh_h[i] = h;
  g_whh_l[i] = (_Float16)(v - (float)h);
}

__global__ void k_copy(const float* __restrict__ src, int which, int off, int n) {
  int i = blockIdx.x * 256 + threadIdx.x;
  if (i >= n) return;
  float* D = which == 0 ? g_b0 : which == 1 ? g_b1 : g_bo;
  D[off + i] = src[i];
}

__global__ void k_pad() {
  int i = blockIdx.x * 256 + threadIdx.x;
  if (i < 48 * 512 - 44 * 512) {            // zero pad rows 44..47 of w_out
    g_wout_h[44 * 512 + i] = (_Float16)0.f;
    g_wout_l[44 * 512 + i] = (_Float16)0.f;
  }
  if (i < 4) g_bo[44 + i] = 0.f;
}

__global__ void k_rev(const int* __restrict__ lengths) {
  int i = blockIdx.x * 256 + threadIdx.x;
  if (i >= BT) return;
  int b = i >> 10, t = i & 1023;
  int len = lengths[b];
  int r = (t < len) ? (len - 1 - t) : t;
  g_rev[i] = (b << 10) | r;
}

// x (B,F,T) -> xt rows (b*T+t, d) split to f16 hi/lo
__global__ void k_xpose(const float* __restrict__ x) {
  __shared__ float tile[32][33];
  int t0 = blockIdx.x * 32, d0 = blockIdx.y * 32, b = blockIdx.z;
  int tx = threadIdx.x, ty = threadIdx.y;
  #pragma unroll
  for (int i = 0; i < 4; i++) {
    int d = d0 + ty + i * 8;
    tile[ty + i * 8][tx] = x[((size_t)b * Fn + d) * Tn + t0 + tx];
  }
  __syncthreads();
  #pragma unroll
  for (int i = 0; i < 4; i++) {
    int t = t0 + ty + i * 8;
    float v = tile[tx][ty + i * 8];
    _Float16 h = (_Float16)v;
    size_t o = ((size_t)b * Tn + t) * Fn + d0 + tx;
    g_xt_h[o] = h;
    g_xt_l[o] = (_Float16)(v - (float)h);
  }
}

// ---------------- generic dual-f16 MFMA GEMM ----------------
// SEL: 0 = proj layer0 (A=xt,K=128), 1 = proj layer1 (A=f0,K=512), 2 = emissions (A=f1,N=48->44)
template <int SEL, int NPL>
__global__ __launch_bounds__(256) void k_gemm() {
  constexpr int KD = SEL == 0 ? 128 : 512;
  constexpr int WM = SEL == 2 ? 4 : 2;
  constexpr int WN = SEL == 2 ? 1 : 2;
  constexpr int MW = SEL == 2 ? 2 : 4;
  constexpr int NW = SEL == 2 ? 3 : 4;
  constexpr int LDO = SEL == 2 ? 44 : 2048;
  constexpr int NCOL = SEL == 2 ? 44 : 2048;
  constexpr int NSPLIT = SEL == 2 ? (1 << 30) : 1024;
  const _Float16* Ah = SEL == 0 ? g_xt_h : SEL == 1 ? g_f0_h : g_f1_h;
  const _Float16* Al = SEL == 0 ? g_xt_l : SEL == 1 ? g_f0_l : g_f1_l;
  const _Float16* Bh = SEL == 0 ? g_wih0_h : SEL == 1 ? g_wih1_h : g_wout_h;
  const _Float16* Bl = SEL == 0 ? g_wih0_l : SEL == 1 ? g_wih1_l : g_wout_l;
  const float* bias = SEL == 0 ? g_b0 : SEL == 1 ? g_b1 : g_bo;
  float* out = SEL == 2 ? g_em : g_xg;

  const int lane = threadIdx.x & 63, wv = threadIdx.x >> 6;
  const int wm = wv / WN, wn = wv % WN;
  const int c = lane & 15, q = lane >> 4;
  const int bm0 = blockIdx.x * (WM * MW * 16);
  const int bn0 = blockIdx.y * (WN * NW * 16);
  const bool bw = bn0 >= NSPLIT;   // backward-direction column block -> gathered A rows
  int arow[MW];
  #pragma unroll
  for (int mi = 0; mi < MW; mi++) {
    int r = bm0 + (wm * MW + mi) * 16 + c;
    arow[mi] = bw ? g_rev[r] : r;
  }
  f32x4 acc[MW][NW];
  #pragma unroll
  for (int mi = 0; mi < MW; mi++)
    #pragma unroll
    for (int ni = 0; ni < NW; ni++) acc[mi][ni] = f32x4{0.f, 0.f, 0.f, 0.f};

  for (int kc = 0; kc < KD / 32; kc++) {
    const int k = kc * 32 + q * 8;
    f16x8 ah[MW], al[MW], bh[NW], bl[NW];
    #pragma unroll
    for (int mi = 0; mi < MW; mi++) {
      ah[mi] = *(const f16x8*)(Ah + (size_t)arow[mi] * KD + k);
      if constexpr (NPL > 1) al[mi] = *(const f16x8*)(Al + (size_t)arow[mi] * KD + k);
    }
    #pragma unroll
    for (int ni = 0; ni < NW; ni++) {
      int n = bn0 + (wn * NW + ni) * 16 + c;
      bh[ni] = *(const f16x8*)(Bh + (size_t)n * KD + k);
      if constexpr (NPL > 1) bl[ni] = *(const f16x8*)(Bl + (size_t)n * KD + k);
    }
    #pragma unroll
    for (int mi = 0; mi < MW; mi++)
      #pragma unroll
      for (int ni = 0; ni < NW; ni++) {
        acc[mi][ni] = mfma_(ah[mi], bh[ni], acc[mi][ni]);
        if constexpr (NPL > 1) {
          acc[mi][ni] = mfma_(ah[mi], bl[ni], acc[mi][ni]);
          acc[mi][ni] = mfma_(al[mi], bh[ni], acc[mi][ni]);
        }
      }
  }
  #pragma unroll
  for (int mi = 0; mi < MW; mi++)
    #pragma unroll
    for (int ni = 0; ni < NW; ni++) {
      int col = bn0 + (wn * NW + ni) * 16 + c;
      if (col < NCOL) {
        int row0 = bm0 + (wm * MW + mi) * 16 + q * 4;
        float bv = bias[col];
        #pragma unroll
        for (int r = 0; r < 4; r++)
          out[(size_t)(row0 + r) * LDO + col] = acc[mi][ni][r] + bv;
      }
    }
}

// ---------------- LSTM recurrence: oct of 8 wgs per (bg,dir), W_hh in LDS ----------------
// Round-14 proven structure (3.95ms/layer): after B1, gate waves run the nonlinearity,
// issue the 16B staging stores, drain wave-locally, post their half-flag, THEN do the
// scattered fh/fl HBM stores (off the flag critical path). 16 dedicated pollers in
// wave 7 watch one half-flag line each; B3 releases the wg; 1-RTT 4xu64 staged read;
// B4 publishes. All atomics RELAXED agent-scope (LLC-serviced, no cache maintenance).
__global__ __launch_bounds__(512, 1) void k_rec3(const float* __restrict__ h0,
                                                 const float* __restrict__ c0, int layer) {
  __shared__ __align__(16) _Float16 Wh_l[8][8][512];      // 64 KB
  __shared__ __align__(16) _Float16 Wl_l[8][8][512];      // 64 KB
  __shared__ __align__(16) _Float16 lh[4096], ll[4096];   // 16 KB
  __shared__ float gbuf[2][3][16][16];                    // 6 KB
  const int tid = threadIdx.x, lane = tid & 63, w = tid >> 6;  // 8 waves
  const int c = lane & 15, q = lane >> 4;
  const int bg = blockIdx.x, d = blockIdx.y, s = blockIdx.z;
  const int dirIdx = layer * 2 + d;
  const int g = w >> 1, hm = w & 1;
  const int m = 2 * s + hm;            // unit-tile 0..15
  const int nt = g * 16 + m;           // gate tile 0..63
  const int u = m * 16 + c;            // global unit 0..255
  const _Float16* whp = g_whh_h + (size_t)dirIdx * (Gn * Hn);
  const _Float16* wlp = g_whh_l + (size_t)dirIdx * (Gn * Hn);
  _Float16* fh = layer ? g_f1_h : g_f0_h;
  _Float16* fl = layer ? g_f1_l : g_f0_l;
  const float* h0p = h0 + ((size_t)dirIdx * Bn + bg * 16) * Hn;
  const float* c0p = c0 + ((size_t)dirIdx * Bn + bg * 16) * Hn;

  // W slice -> LDS (once)
  #pragma unroll
  for (int kc = 0; kc < 8; kc++) {
    *(f16x8*)&Wh_l[w][kc][lane * 8] =
        *(const f16x8*)(whp + ((size_t)(nt * 8 + kc) * 64 + lane) * 8);
    *(f16x8*)&Wl_l[w][kc][lane * 8] =
        *(const f16x8*)(wlp + ((size_t)(nt * 8 + kc) * 64 + lane) * 8);
  }
  // h0 -> fragment LDS
  for (int i = tid; i < 4096; i += 512) {
    int j = i & 7, ln = (i >> 3) & 63, kc = i >> 9;
    int row = ln & 15, uu = kc * 32 + ((ln >> 4) * 8) + j;
    float v = h0p[row * Hn + uu];
    _Float16 hv = (_Float16)v;
    lh[i] = hv;
    ll[i] = (_Float16)(v - (float)hv);
  }
  float creg[4];
  if (g == 0) {
    #pragma unroll
    for (int r = 0; r < 4; r++) creg[r] = c0p[(4 * q + r) * Hn + u];
  }
  // xg addressing: col = d*1024 + g*256 + u
  size_t xoff[4];
  #pragma unroll
  for (int r = 0; r < 4; r++)
    xoff[r] = ((size_t)(bg * 16 + 4 * q + r) * Tn) * 2048 + (size_t)d * 1024;
  const int col = g * 256 + u;
  // staging index for this lane's unit (row term added per r)
  const int fb = (((u >> 5) * 64 + ((u >> 3) & 3) * 16) * 8) + (u & 7);

  float xgv[4];
  #pragma unroll
  for (int r = 0; r < 4; r++) xgv[r] = g_xg[xoff[r] + col];
  __syncthreads();

  for (int t = 0; t < Tn; t++) {
    f32x4 acc;
    #pragma unroll
    for (int r = 0; r < 4; r++) acc[r] = xgv[r];

    #pragma unroll
    for (int kc = 0; kc < 8; kc++) {
      f16x8 ah = *(const f16x8*)(lh + (kc * 64 + lane) * 8);
      f16x8 al = *(const f16x8*)(ll + (kc * 64 + lane) * 8);
      f16x8 wh = *(const f16x8*)&Wh_l[w][kc][lane * 8];
      f16x8 wl = *(const f16x8*)&Wl_l[w][kc][lane * 8];
      acc = mfma_(ah, wh, acc);
      acc = mfma_(ah, wl, acc);
      acc = mfma_(al, wh, acc);
    }

    if (g != 0) {
      #pragma unroll
      for (int r = 0; r < 4; r++) gbuf[hm][g - 1][4 * q + r][c] = acc[r];
    }
    __syncthreads();   // B1: gbuf ready; all LDS reads of lh/ll done

    const bool more = (t + 1 < Tn);
    if (g == 0) {
      _Float16 hvs[4], lvs[4];
      #pragma unroll
      for (int r = 0; r < 4; r++) {
        float gi = acc[r];
        float gf = gbuf[hm][0][4 * q + r][c];
        float gg = gbuf[hm][1][4 * q + r][c];
        float go = gbuf[hm][2][4 * q + r][c];
        float cn = sigf(gf) * creg[r] + sigf(gi) * tanh_(gg);
        float hn = sigf(go) * tanh_(cn);
        creg[r] = cn;
        hvs[r] = (_Float16)hn;
        lvs[r] = (_Float16)(hn - (float)hvs[r]);
        if (more) {
          unsigned int pk = (unsigned int)__builtin_bit_cast(unsigned short, hvs[r]) |
                            ((unsigned int)__builtin_bit_cast(unsigned short, lvs[r]) << 16);
          __hip_atomic_store(&g_hxs[t & 1][bg][d][fb + (4 * q + r) * 8], pk,
                             __ATOMIC_RELAXED, __HIP_MEMORY_SCOPE_AGENT);
        }
      }
      if (more) {
        // wave-local drain: ONLY the 16B staging stores precede this in-flight
        asm volatile("s_waitcnt vmcnt(0)" ::: "memory");
        if (lane == 0)
          __hip_atomic_store(&g_syncp[layer][bg][d][s][hm][0], t + 1,
                             __ATOMIC_RELAXED, __HIP_MEMORY_SCOPE_AGENT);
      }
      // scattered fh/fl HBM stores AFTER the flag post (off the critical path)
      #pragma unroll
      for (int r = 0; r < 4; r++) {
        int bi = bg * 16 + 4 * q + r;
        int rv = (d == 0) ? bi * Tn + t : g_rev[bi * Tn + t];
        size_t fo = (size_t)rv * 512 + d * 256 + u;
        fh[fo] = hvs[r];
        fl[fo] = lvs[r];
      }
    }

    if (more) {
      // xg prefetch for t+1 — flies under the flag wait
      float xn[4];
      #pragma unroll
      for (int r = 0; r < 4; r++)
        xn[r] = g_xg[xoff[r] + (size_t)(t + 1) * 2048 + col];

      // 16 pollers in wave 7 (idle after B1), one half-flag line each
      if (w == 7 && lane < 16) {
        const int* fp = &g_syncp[layer][bg][d][lane >> 1][lane & 1][0];
        while (__hip_atomic_load(fp, __ATOMIC_RELAXED, __HIP_MEMORY_SCOPE_AGENT) < t + 1)
          __builtin_amdgcn_s_sleep(1);
      }
      __syncthreads();   // B3: all producers' flags observed

      // 4 unrolled 64-bit LLC loads (issued concurrently) + in-register unpack
      const unsigned long long* s64 =
          (const unsigned long long*)&g_hxs[t & 1][bg][d][0];
      unsigned long long p0 = __hip_atomic_load(s64 + tid * 4 + 0, __ATOMIC_RELAXED,
                                                __HIP_MEMORY_SCOPE_AGENT);
      unsigned long long p1 = __hip_atomic_load(s64 + tid * 4 + 1, __ATOMIC_RELAXED,
                                                __HIP_MEMORY_SCOPE_AGENT);
      unsigned long long p2 = __hip_atomic_load(s64 + tid * 4 + 2, __ATOMIC_RELAXED,
                                                __HIP_MEMORY_SCOPE_AGENT);
      unsigned long long p3 = __hip_atomic_load(s64 + tid * 4 + 3, __ATOMIC_RELAXED,
                                                __HIP_MEMORY_SCOPE_AGENT);
      unsigned int w0 = (unsigned int)p0, w1 = (unsigned int)(p0 >> 32);
      unsigned int w2 = (unsigned int)p1, w3 = (unsigned int)(p1 >> 32);
      unsigned int w4 = (unsigned int)p2, w5 = (unsigned int)(p2 >> 32);
      unsigned int w6 = (unsigned int)p3, w7 = (unsigned int)(p3 >> 32);
      uint4 hiw, low;
      hiw.x = (w0 & 0xffffu) | (w1 << 16);
      hiw.y = (w2 & 0xffffu) | (w3 << 16);
      hiw.z = (w4 & 0xffffu) | (w5 << 16);
      hiw.w = (w6 & 0xffffu) | (w7 << 16);
      low.x = (w0 >> 16) | (w1 & 0xffff0000u);
      low.y = (w2 >> 16) | (w3 & 0xffff0000u);
      low.z = (w4 >> 16) | (w5 & 0xffff0000u);
      low.w = (w6 >> 16) | (w7 & 0xffff0000u);
      *(uint4*)&lh[tid * 8] = hiw;
      *(uint4*)&ll[tid * 8] = low;

      __syncthreads();   // B4: new h visible wg-wide
      #pragma unroll
      for (int r = 0; r < 4; r++) xgv[r] = xn[r];
    }
  }
}

// ---------------- CRF scan, split into two concurrent serial chains ----------------
// Blocks 0..63: alpha (log-sum-exp) chain + llh.  Blocks 64..127: Viterbi chain +
// hist + last. The chains are independent; running them on different CUs halves the
// per-step latency chain of each. 8-step em batch prefetch in both.
__global__ __launch_bounds__(64) void k_scan2(const int* __restrict__ lengths,
                                              const int* __restrict__ y_true,
                                              const float* __restrict__ start,
                                              const float* __restrict__ endt,
                                              const float* __restrict__ trans) {
  const int b = blockIdx.x & 63, mode = blockIdx.x >> 6, j = threadIdx.x;
  const int V = lengths[b] * 4;
  const float* em = g_em + (size_t)b * (Tn * 44);
  float tcol[11];
  #pragma unroll
  for (int i = 0; i < 11; i++) tcol[i] = (j < 11) ? trans[i * 11 + j] : 0.f;

  if (mode == 0) {
    // ---------- alpha chain ----------
    float alpha = (j < 11) ? start[j] + em[j] : -1e30f;
    for (int s0 = 1; s0 < V; s0 += 8) {
      float eb[8];
      #pragma unroll
      for (int k = 0; k < 8; k++) {
        int s = s0 + k;
        eb[k] = (j < 11 && s < Sn) ? em[s * 11 + j] : 0.f;
      }
      #pragma unroll
      for (int k = 0; k < 8; k++) {
        int s = s0 + k;
        if (s < V) {
          float av[11];
          float m = -1e30f;
          #pragma unroll
          for (int i = 0; i < 11; i++) {
            float va = __shfl(alpha, i) + tcol[i];
            av[i] = va;
            m = fmaxf(m, va);
          }
          float sum = 0.f;
          #pragma unroll
          for (int i = 0; i < 11; i++) sum += __expf(av[i] - m);
          alpha = eb[k] + m + __logf(sum);
        }
      }
    }
    float ae = (j < 11) ? alpha + endt[j] : -1e30f;
    float m2 = -1e30f;
    #pragma unroll
    for (int i = 0; i < 11; i++) m2 = fmaxf(m2, __shfl(ae, i));
    float s2 = 0.f;
    #pragma unroll
    for (int i = 0; i < 11; i++) s2 += __expf(__shfl(ae, i) - m2);
    float logZ = m2 + __logf(s2);
    const int* y = y_true + (size_t)b * Sn;
    float part = 0.f;
    for (int s = 1 + j; s < V; s += 64) {
      int yp = y[s - 1], yc = y[s];
      part += trans[yp * 11 + yc] + em[s * 11 + yc];
    }
    #pragma unroll
    for (int off = 32; off > 0; off >>= 1) part += __shfl_down(part, off);
    if (j == 0) {
      int y0 = y[0];
      float num = start[y0] + em[y0] + part + endt[y[V - 1]];
      g_llh[b] = num - logZ;
    }
  } else {
    // ---------- Viterbi chain ----------
    float score = (j < 11) ? start[j] + em[j] : -1e30f;
    for (int s0 = 1; s0 < V; s0 += 8) {
      float eb[8];
      #pragma unroll
      for (int k = 0; k < 8; k++) {
        int s = s0 + k;
        eb[k] = (j < 11 && s < Sn) ? em[s * 11 + j] : 0.f;
      }
      #pragma unroll
      for (int k = 0; k < 8; k++) {
        int s = s0 + k;
        if (s < V) {
          float bestv = -1e30f;
          int bi = 0;
          #pragma unroll
          for (int i = 0; i < 11; i++) {
            float vs = __shfl(score, i) + tcol[i];
            if (vs > bestv) { bestv = vs; bi = i; }  // first-wins argmax
          }
          score = bestv + eb[k];
          if (j < 11) g_hist[(size_t)s * (Bn * NTn) + b * NTn + j] = (unsigned char)bi;
        }
      }
    }
    float se = (j < 11) ? score + endt[j] : -1e30f;
    float bv = -1e30f;
    int bj = 0;
    #pragma unroll
    for (int i = 0; i < 11; i++) {
      float v = __shfl(se, i);
      if (v > bv) { bv = v; bj = i; }
    }
    if (j == 0) g_last[b] = bj;
  }
}

// ---------------- Viterbi backtrace (double-buffered) + loss reduce ----------------
__global__ __launch_bounds__(256) void k_back(const int* __restrict__ lengths,
                                              float* __restrict__ out) {
  __shared__ unsigned char hbuf[2][64 * Bn * NTn];  // 2 x 45056 B
  const int tid = threadIdx.x;
  if (tid == 0) {
    float ssum = 0.f;
    for (int b = 0; b < Bn; b++) ssum += g_llh[b];
    out[0] = -ssum / (float)Bn;
  }
  int carry = 0, V = 0;
  if (tid < 64) {
    carry = g_last[tid];
    V = lengths[tid] * 4;
    out[1 + (size_t)tid * Sn + (Sn - 1)] = (float)carry;
  }
  constexpr int CHW = 64 * Bn * NTn / 4;   // dwords per chunk
  const int nc = Sn / 64;                   // 64 chunks
  {
    const unsigned int* src =
        (const unsigned int*)(g_hist + (size_t)(nc - 1) * 64 * (Bn * NTn));
    unsigned int* dst = (unsigned int*)hbuf[(nc - 1) & 1];
    for (int i = tid; i < CHW; i += 256) dst[i] = src[i];
  }
  __syncthreads();
  for (int c = nc - 1; c >= 0; c--) {
    if (c > 0 && tid >= 64) {   // threads 64..255 prefetch chunk c-1
      const unsigned int* src =
          (const unsigned int*)(g_hist + (size_t)(c - 1) * 64 * (Bn * NTn));
      unsigned int* dst = (unsigned int*)hbuf[(c - 1) & 1];
      for (int i = tid - 64; i < CHW; i += 192) dst[i] = src[i];
    }
    if (tid < 64) {             // lanes 0..63 backtrace chunk c
      const unsigned char* hb = hbuf[c & 1];
      const int s0 = c * 64;
      for (int s = s0 + 63; s >= s0 && s >= 1; s--) {
        int pr = hb[(s - s0) * (Bn * NTn) + tid * NTn + carry];
        if (s < V) carry = pr;
        out[1 + (size_t)tid * Sn + (s - 1)] = (float)carry;
      }
    }
    __syncthreads();
  }
}

// ---------------- host ----------------
extern "C" void kernel_launch(void* const* d_in, const int* in_sizes, int n_in,
                              void* d_out, int out_size, void* d_ws, size_t ws_size,
                              hipStream_t stream) {
  (void)in_sizes; (void)n_in; (void)d_ws; (void)ws_size; (void)out_size;
  const float* x        = (const float*)d_in[0];
  const int*   y_true   = (const int*)d_in[1];
  const int*   lengths  = (const int*)d_in[2];
  const float* h0       = (const float*)d_in[3];
  const float* c0       = (const float*)d_in[4];
  const float* w_ih_l0  = (const float*)d_in[5];
  const float* w_hh_l0  = (const float*)d_in[6];
  const float* b_l0     = (const float*)d_in[7];
  const float* w_ih_l0r = (const float*)d_in[8];
  const float* w_hh_l0r = (const float*)d_in[9];
  const float* b_l0r    = (const float*)d_in[10];
  const float* w_ih_l1  = (const float*)d_in[11];
  const float* w_hh_l1  = (const float*)d_in[12];
  const float* b_l1     = (const float*)d_in[13];
  const float* w_ih_l1r = (const float*)d_in[14];
  const float* w_hh_l1r = (const float*)d_in[15];
  const float* b_l1r    = (const float*)d_in[16];
  const float* w_out    = (const float*)d_in[17];
  const float* b_out    = (const float*)d_in[18];
  const float* start_t  = (const float*)d_in[19];
  const float* end_t    = (const float*)d_in[20];
  const float* trans    = (const float*)d_in[21];
  float* out = (float*)d_out;

  auto gs = [](int n) { return dim3((n + 255) / 256); };
  dim3 b256(256);

  // weight prep + sync-flag reset (runs every call for graph-replay determinism)
  k_zinit<<<gs(4096), b256, 0, stream>>>();
  k_wswz<<<gs(4 * Gn * Hn), b256, 0, stream>>>(w_hh_l0, w_hh_l0r, w_hh_l1, w_hh_l1r);
  k_split<<<gs(131072), b256, 0, stream>>>(w_ih_l0, 1, 0, 131072);
  k_split<<<gs(131072), b256, 0, stream>>>(w_ih_l0r, 1, 131072, 131072);
  k_split<<<gs(524288), b256, 0, stream>>>(w_ih_l1, 2, 0, 524288);
  k_split<<<gs(524288), b256, 0, stream>>>(w_ih_l1r, 2, 524288, 524288);
  k_split<<<gs(22528), b256, 0, stream>>>(w_out, 3, 0, 22528);
  k_copy<<<gs(1024), b256, 0, stream>>>(b_l0, 0, 0, 1024);
  k_copy<<<gs(1024), b256, 0, stream>>>(b_l0r, 0, 1024, 1024);
  k_copy<<<gs(1024), b256, 0, stream>>>(b_l1, 1, 0, 1024);
  k_copy<<<gs(1024), b256, 0, stream>>>(b_l1r, 1, 1024, 1024);
  k_copy<<<gs(44), b256, 0, stream>>>(b_out, 2, 0, 44);
  k_pad<<<gs(2048), b256, 0, stream>>>();
  k_rev<<<gs(BT), b256, 0, stream>>>(lengths);
  k_xpose<<<dim3(Tn / 32, Fn / 32, Bn), dim3(32, 8), 0, stream>>>(x);

  // layer 0
  k_gemm<0, 3><<<dim3(BT / 128, 16), b256, 0, stream>>>();
  k_rec3<<<dim3(4, 2, 8), dim3(512), 0, stream>>>(h0, c0, 0);
  // layer 1
  k_gemm<1, 3><<<dim3(BT / 128, 16), b256, 0, stream>>>();
  k_rec3<<<dim3(4, 2, 8), dim3(512), 0, stream>>>(h0, c0, 1);
  // emissions
  k_gemm<2, 3><<<dim3(BT / 128, 1), b256, 0, stream>>>();
  // CRF + viterbi (two concurrent serial chains)
  k_scan2<<<dim3(128), dim3(64), 0, stream>>>(lengths, y_true, start_t, end_t, trans);
  k_back<<<dim3(1), b256, 0, stream>>>(lengths, out);
}

// Round 19
// 11006.181 us; speedup vs baseline: 1.6526x; 1.0410x over previous
//
#include <hip/hip_runtime.h>
#include <hip/hip_bf16.h>

typedef _Float16 f16x8 __attribute__((ext_vector_type(8)));
typedef float f32x4 __attribute__((ext_vector_type(4)));

#define DI static __device__ __forceinline__

constexpr int Bn = 64, Fn = 128, Tn = 1024, Hn = 256, NTn = 11;
constexpr int BT = Bn * Tn;       // 65536
constexpr int Gn = 4 * Hn;        // 1024
constexpr int Sn = 4 * Tn;        // 4096

// ---------------- device global buffers (no d_ws use) ----------------
__device__ __align__(16) _Float16 g_xt_h[BT * Fn];
__device__ __align__(16) _Float16 g_xt_l[BT * Fn];
__device__ __align__(16) _Float16 g_f0_h[BT * 512];
__device__ __align__(16) _Float16 g_f0_l[BT * 512];
__device__ __align__(16) _Float16 g_f1_h[BT * 512];
__device__ __align__(16) _Float16 g_f1_l[BT * 512];
__device__ __align__(16) float    g_xg[(size_t)BT * 2048];   // 512MB, reused per layer
__device__ __align__(16) _Float16 g_whh_h[4 * Gn * Hn];      // fragment-swizzled
__device__ __align__(16) _Float16 g_whh_l[4 * Gn * Hn];
__device__ __align__(16) _Float16 g_wih0_h[2048 * Fn];
__device__ __align__(16) _Float16 g_wih0_l[2048 * Fn];
__device__ __align__(16) _Float16 g_wih1_h[2048 * 512];
__device__ __align__(16) _Float16 g_wih1_l[2048 * 512];
__device__ __align__(16) _Float16 g_wout_h[48 * 512];
__device__ __align__(16) _Float16 g_wout_l[48 * 512];
__device__ float g_b0[2048], g_b1[2048], g_bo[48];
__device__ float g_em[BT * 44];
__device__ __align__(4) unsigned char g_hist[(size_t)Sn * Bn * NTn];
__device__ int   g_rev[BT];
__device__ float g_llh[Bn];
__device__ int   g_last[Bn];
// cross-wg h staging: [parity][bg][d][fragidx] packed (hi | lo<<16)
__device__ unsigned int g_hxs[2][4][2][4096];
// per-producer half-flags: [layer][bg][d][prod][hm][16 ints pad = 64B/flag]
__device__ int g_syncp[2][4][2][8][2][16];

DI f32x4 mfma_(f16x8 a, f16x8 b, f32x4 c) {
  return __builtin_amdgcn_mfma_f32_16x16x32_f16(a, b, c, 0, 0, 0);
}
DI float sigf(float x) { return 1.f / (1.f + __expf(-x)); }
DI float tanh_(float x) { return 1.f - 2.f / (1.f + __expf(2.f * x)); }
DI float max11(const float* v) {   // 4-deep tree (v_max3-friendly)
  return fmaxf(
      fmaxf(fmaxf(fmaxf(v[0], v[1]), fmaxf(v[2], v[3])),
            fmaxf(fmaxf(v[4], v[5]), fmaxf(v[6], v[7]))),
      fmaxf(fmaxf(v[8], v[9]), v[10]));
}

// ---------------- prep kernels ----------------
__global__ void k_zinit() {
  int i = blockIdx.x * 256 + threadIdx.x;
  if (i < 2 * 4 * 2 * 8 * 2 * 16) ((int*)g_syncp)[i] = 0;
}

__global__ void k_split(const float* __restrict__ src, int which, int off, int n) {
  int i = blockIdx.x * 256 + threadIdx.x;
  if (i >= n) return;
  float v = src[i];
  _Float16 h = (_Float16)v;
  _Float16 l = (_Float16)(v - (float)h);
  _Float16 *H, *L;
  switch (which) {
    case 1:  H = g_wih0_h; L = g_wih0_l; break;
    case 2:  H = g_wih1_h; L = g_wih1_l; break;
    default: H = g_wout_h; L = g_wout_l; break;
  }
  H[off + i] = h; L[off + i] = l;
}

// W_hh -> fragment-contiguous swizzle: idx = (((nt*8 + kc)*64 + lane)*8 + j)
// holds W[nt*16 + (lane&15)][kc*32 + (lane>>4)*8 + j]
__global__ void k_wswz(const float* __restrict__ w0, const float* __restrict__ w1,
                       const float* __restrict__ w2, const float* __restrict__ w3) {
  int i = blockIdx.x * 256 + threadIdx.x;
  if (i >= 4 * Gn * Hn) return;
  int mat = i >> 18;
  int e = i & 262143;
  int nt = e >> 12, rem = e & 4095;
  int kc = rem >> 9;
  int rem2 = rem & 511;
  int lane = rem2 >> 3, j = rem2 & 7;
  int row = nt * 16 + (lane & 15);
  int col = kc * 32 + (lane >> 4) * 8 + j;
  const float* src = mat == 0 ? w0 : mat == 1 ? w1 : mat == 2 ? w2 : w3;
  float v = src[row * Hn + col];
  _Float16 h = (_Float16)v;
  g_whh_h[i] = h;
  g_whh_l[i] = (_Float16)(v - (float)h);
}

// biases + w_out row padding, one launch
__global__ void k_bias(const float* __restrict__ b0a, const float* __restrict__ b0b,
                       const float* __restrict__ b1a, const float* __restrict__ b1b,
                       const float* __restrict__ bo) {
  int i = blockIdx.x * 256 + threadIdx.x;
  if (i < 1024) {
    g_b0[i] = b0a[i];
    g_b0[1024 + i] = b0b[i];
    g_b1[i] = b1a[i];
    g_b1[1024 + i] = b1b[i];
  }
  if (i < 44) g_bo[i] = bo[i];
  if (i >= 44 && i < 48) g_bo[i] = 0.f;
  if (i < 2048) {                     // zero pad rows 44..47 of w_out
    g_wout_h[44 * 512 + i] = (_Float16)0.f;
    g_wout_l[44 * 512 + i] = (_Float16)0.f;
  }
}

__global__ void k_rev(const int* __restrict__ lengths) {
  int i = blockIdx.x * 256 + threadIdx.x;
  if (i >= BT) return;
  int b = i >> 10, t = i & 1023;
  int len = lengths[b];
  int r = (t < len) ? (len - 1 - t) : t;
  g_rev[i] = (b << 10) | r;
}

// x (B,F,T) -> xt rows (b*T+t, d) split to f16 hi/lo
__global__ void k_xpose(const float* __restrict__ x) {
  __shared__ float tile[32][33];
  int t0 = blockIdx.x * 32, d0 = blockIdx.y * 32, b = blockIdx.z;
  int tx = threadIdx.x, ty = threadIdx.y;
  #pragma unroll
  for (int i = 0; i < 4; i++) {
    int d = d0 + ty + i * 8;
    tile[ty + i * 8][tx] = x[((size_t)b * Fn + d) * Tn + t0 + tx];
  }
  __syncthreads();
  #pragma unroll
  for (int i = 0; i < 4; i++) {
    int t = t0 + ty + i * 8;
    float v = tile[tx][ty + i * 8];
    _Float16 h = (_Float16)v;
    size_t o = ((size_t)b * Tn + t) * Fn + d0 + tx;
    g_xt_h[o] = h;
    g_xt_l[o] = (_Float16)(v - (float)h);
  }
}

// ---------------- generic dual-f16 MFMA GEMM ----------------
// SEL: 0 = proj layer0 (A=xt,K=128), 1 = proj layer1 (A=f0,K=512), 2 = emissions (A=f1,N=48->44)
template <int SEL, int NPL>
__global__ __launch_bounds__(256) void k_gemm() {
  constexpr int KD = SEL == 0 ? 128 : 512;
  constexpr int WM = SEL == 2 ? 4 : 2;
  constexpr int WN = SEL == 2 ? 1 : 2;
  constexpr int MW = SEL == 2 ? 2 : 4;
  constexpr int NW = SEL == 2 ? 3 : 4;
  constexpr int LDO = SEL == 2 ? 44 : 2048;
  constexpr int NCOL = SEL == 2 ? 44 : 2048;
  constexpr int NSPLIT = SEL == 2 ? (1 << 30) : 1024;
  const _Float16* Ah = SEL == 0 ? g_xt_h : SEL == 1 ? g_f0_h : g_f1_h;
  const _Float16* Al = SEL == 0 ? g_xt_l : SEL == 1 ? g_f0_l : g_f1_l;
  const _Float16* Bh = SEL == 0 ? g_wih0_h : SEL == 1 ? g_wih1_h : g_wout_h;
  const _Float16* Bl = SEL == 0 ? g_wih0_l : SEL == 1 ? g_wih1_l : g_wout_l;
  const float* bias = SEL == 0 ? g_b0 : SEL == 1 ? g_b1 : g_bo;
  float* out = SEL == 2 ? g_em : g_xg;

  const int lane = threadIdx.x & 63, wv = threadIdx.x >> 6;
  const int wm = wv / WN, wn = wv % WN;
  const int c = lane & 15, q = lane >> 4;
  const int bm0 = blockIdx.x * (WM * MW * 16);
  const int bn0 = blockIdx.y * (WN * NW * 16);
  const bool bw = bn0 >= NSPLIT;   // backward-direction column block -> gathered A rows
  int arow[MW];
  #pragma unroll
  for (int mi = 0; mi < MW; mi++) {
    int r = bm0 + (wm * MW + mi) * 16 + c;
    arow[mi] = bw ? g_rev[r] : r;
  }
  f32x4 acc[MW][NW];
  #pragma unroll
  for (int mi = 0; mi < MW; mi++)
    #pragma unroll
    for (int ni = 0; ni < NW; ni++) acc[mi][ni] = f32x4{0.f, 0.f, 0.f, 0.f};

  for (int kc = 0; kc < KD / 32; kc++) {
    const int k = kc * 32 + q * 8;
    f16x8 ah[MW], al[MW], bh[NW], bl[NW];
    #pragma unroll
    for (int mi = 0; mi < MW; mi++) {
      ah[mi] = *(const f16x8*)(Ah + (size_t)arow[mi] * KD + k);
      if constexpr (NPL > 1) al[mi] = *(const f16x8*)(Al + (size_t)arow[mi] * KD + k);
    }
    #pragma unroll
    for (int ni = 0; ni < NW; ni++) {
      int n = bn0 + (wn * NW + ni) * 16 + c;
      bh[ni] = *(const f16x8*)(Bh + (size_t)n * KD + k);
      if constexpr (NPL > 1) bl[ni] = *(const f16x8*)(Bl + (size_t)n * KD + k);
    }
    #pragma unroll
    for (int mi = 0; mi < MW; mi++)
      #pragma unroll
      for (int ni = 0; ni < NW; ni++) {
        acc[mi][ni] = mfma_(ah[mi], bh[ni], acc[mi][ni]);
        if constexpr (NPL > 1) {
          acc[mi][ni] = mfma_(ah[mi], bl[ni], acc[mi][ni]);
          acc[mi][ni] = mfma_(al[mi], bh[ni], acc[mi][ni]);
        }
      }
  }
  #pragma unroll
  for (int mi = 0; mi < MW; mi++)
    #pragma unroll
    for (int ni = 0; ni < NW; ni++) {
      int col = bn0 + (wn * NW + ni) * 16 + c;
      if (col < NCOL) {
        int row0 = bm0 + (wm * MW + mi) * 16 + q * 4;
        float bv = bias[col];
        #pragma unroll
        for (int r = 0; r < 4; r++)
          out[(size_t)(row0 + r) * LDO + col] = acc[mi][ni][r] + bv;
      }
    }
}

// ---------------- LSTM recurrence: oct of 8 wgs per (bg,dir), W_hh in LDS ----------------
// Round-14 proven structure (3.95ms/layer, latency floor established over rounds 10-17).
__global__ __launch_bounds__(512, 1) void k_rec3(const float* __restrict__ h0,
                                                 const float* __restrict__ c0, int layer) {
  __shared__ __align__(16) _Float16 Wh_l[8][8][512];      // 64 KB
  __shared__ __align__(16) _Float16 Wl_l[8][8][512];      // 64 KB
  __shared__ __align__(16) _Float16 lh[4096], ll[4096];   // 16 KB
  __shared__ float gbuf[2][3][16][16];                    // 6 KB
  const int tid = threadIdx.x, lane = tid & 63, w = tid >> 6;  // 8 waves
  const int c = lane & 15, q = lane >> 4;
  const int bg = blockIdx.x, d = blockIdx.y, s = blockIdx.z;
  const int dirIdx = layer * 2 + d;
  const int g = w >> 1, hm = w & 1;
  const int m = 2 * s + hm;            // unit-tile 0..15
  const int nt = g * 16 + m;           // gate tile 0..63
  const int u = m * 16 + c;            // global unit 0..255
  const _Float16* whp = g_whh_h + (size_t)dirIdx * (Gn * Hn);
  const _Float16* wlp = g_whh_l + (size_t)dirIdx * (Gn * Hn);
  _Float16* fh = layer ? g_f1_h : g_f0_h;
  _Float16* fl = layer ? g_f1_l : g_f0_l;
  const float* h0p = h0 + ((size_t)dirIdx * Bn + bg * 16) * Hn;
  const float* c0p = c0 + ((size_t)dirIdx * Bn + bg * 16) * Hn;

  // W slice -> LDS (once)
  #pragma unroll
  for (int kc = 0; kc < 8; kc++) {
    *(f16x8*)&Wh_l[w][kc][lane * 8] =
        *(const f16x8*)(whp + ((size_t)(nt * 8 + kc) * 64 + lane) * 8);
    *(f16x8*)&Wl_l[w][kc][lane * 8] =
        *(const f16x8*)(wlp + ((size_t)(nt * 8 + kc) * 64 + lane) * 8);
  }
  // h0 -> fragment LDS
  for (int i = tid; i < 4096; i += 512) {
    int j = i & 7, ln = (i >> 3) & 63, kc = i >> 9;
    int row = ln & 15, uu = kc * 32 + ((ln >> 4) * 8) + j;
    float v = h0p[row * Hn + uu];
    _Float16 hv = (_Float16)v;
    lh[i] = hv;
    ll[i] = (_Float16)(v - (float)hv);
  }
  float creg[4];
  if (g == 0) {
    #pragma unroll
    for (int r = 0; r < 4; r++) creg[r] = c0p[(4 * q + r) * Hn + u];
  }
  // xg addressing: col = d*1024 + g*256 + u
  size_t xoff[4];
  #pragma unroll
  for (int r = 0; r < 4; r++)
    xoff[r] = ((size_t)(bg * 16 + 4 * q + r) * Tn) * 2048 + (size_t)d * 1024;
  const int col = g * 256 + u;
  // staging index for this lane's unit (row term added per r)
  const int fb = (((u >> 5) * 64 + ((u >> 3) & 3) * 16) * 8) + (u & 7);

  float xgv[4];
  #pragma unroll
  for (int r = 0; r < 4; r++) xgv[r] = g_xg[xoff[r] + col];
  __syncthreads();

  for (int t = 0; t < Tn; t++) {
    f32x4 acc;
    #pragma unroll
    for (int r = 0; r < 4; r++) acc[r] = xgv[r];

    #pragma unroll
    for (int kc = 0; kc < 8; kc++) {
      f16x8 ah = *(const f16x8*)(lh + (kc * 64 + lane) * 8);
      f16x8 al = *(const f16x8*)(ll + (kc * 64 + lane) * 8);
      f16x8 wh = *(const f16x8*)&Wh_l[w][kc][lane * 8];
      f16x8 wl = *(const f16x8*)&Wl_l[w][kc][lane * 8];
      acc = mfma_(ah, wh, acc);
      acc = mfma_(ah, wl, acc);
      acc = mfma_(al, wh, acc);
    }

    if (g != 0) {
      #pragma unroll
      for (int r = 0; r < 4; r++) gbuf[hm][g - 1][4 * q + r][c] = acc[r];
    }
    __syncthreads();   // B1: gbuf ready; all LDS reads of lh/ll done

    const bool more = (t + 1 < Tn);
    if (g == 0) {
      _Float16 hvs[4], lvs[4];
      #pragma unroll
      for (int r = 0; r < 4; r++) {
        float gi = acc[r];
        float gf = gbuf[hm][0][4 * q + r][c];
        float gg = gbuf[hm][1][4 * q + r][c];
        float go = gbuf[hm][2][4 * q + r][c];
        float cn = sigf(gf) * creg[r] + sigf(gi) * tanh_(gg);
        float hn = sigf(go) * tanh_(cn);
        creg[r] = cn;
        hvs[r] = (_Float16)hn;
        lvs[r] = (_Float16)(hn - (float)hvs[r]);
        if (more) {
          unsigned int pk = (unsigned int)__builtin_bit_cast(unsigned short, hvs[r]) |
                            ((unsigned int)__builtin_bit_cast(unsigned short, lvs[r]) << 16);
          __hip_atomic_store(&g_hxs[t & 1][bg][d][fb + (4 * q + r) * 8], pk,
                             __ATOMIC_RELAXED, __HIP_MEMORY_SCOPE_AGENT);
        }
      }
      if (more) {
        // wave-local drain: ONLY the 16B staging stores precede this in-flight
        asm volatile("s_waitcnt vmcnt(0)" ::: "memory");
        if (lane == 0)
          __hip_atomic_store(&g_syncp[layer][bg][d][s][hm][0], t + 1,
                             __ATOMIC_RELAXED, __HIP_MEMORY_SCOPE_AGENT);
      }
      // scattered fh/fl HBM stores AFTER the flag post (off the critical path)
      #pragma unroll
      for (int r = 0; r < 4; r++) {
        int bi = bg * 16 + 4 * q + r;
        int rv = (d == 0) ? bi * Tn + t : g_rev[bi * Tn + t];
        size_t fo = (size_t)rv * 512 + d * 256 + u;
        fh[fo] = hvs[r];
        fl[fo] = lvs[r];
      }
    }

    if (more) {
      // xg prefetch for t+1 — flies under the flag wait
      float xn[4];
      #pragma unroll
      for (int r = 0; r < 4; r++)
        xn[r] = g_xg[xoff[r] + (size_t)(t + 1) * 2048 + col];

      // 16 pollers in wave 7 (idle after B1), one half-flag line each
      if (w == 7 && lane < 16) {
        const int* fp = &g_syncp[layer][bg][d][lane >> 1][lane & 1][0];
        while (__hip_atomic_load(fp, __ATOMIC_RELAXED, __HIP_MEMORY_SCOPE_AGENT) < t + 1)
          __builtin_amdgcn_s_sleep(1);
      }
      __syncthreads();   // B3: all producers' flags observed

      // 4 unrolled 64-bit LLC loads (issued concurrently) + in-register unpack
      const unsigned long long* s64 =
          (const unsigned long long*)&g_hxs[t & 1][bg][d][0];
      unsigned long long p0 = __hip_atomic_load(s64 + tid * 4 + 0, __ATOMIC_RELAXED,
                                                __HIP_MEMORY_SCOPE_AGENT);
      unsigned long long p1 = __hip_atomic_load(s64 + tid * 4 + 1, __ATOMIC_RELAXED,
                                                __HIP_MEMORY_SCOPE_AGENT);
      unsigned long long p2 = __hip_atomic_load(s64 + tid * 4 + 2, __ATOMIC_RELAXED,
                                                __HIP_MEMORY_SCOPE_AGENT);
      unsigned long long p3 = __hip_atomic_load(s64 + tid * 4 + 3, __ATOMIC_RELAXED,
                                                __HIP_MEMORY_SCOPE_AGENT);
      unsigned int w0 = (unsigned int)p0, w1 = (unsigned int)(p0 >> 32);
      unsigned int w2 = (unsigned int)p1, w3 = (unsigned int)(p1 >> 32);
      unsigned int w4 = (unsigned int)p2, w5 = (unsigned int)(p2 >> 32);
      unsigned int w6 = (unsigned int)p3, w7 = (unsigned int)(p3 >> 32);
      uint4 hiw, low;
      hiw.x = (w0 & 0xffffu) | (w1 << 16);
      hiw.y = (w2 & 0xffffu) | (w3 << 16);
      hiw.z = (w4 & 0xffffu) | (w5 << 16);
      hiw.w = (w6 & 0xffffu) | (w7 << 16);
      low.x = (w0 >> 16) | (w1 & 0xffff0000u);
      low.y = (w2 >> 16) | (w3 & 0xffff0000u);
      low.z = (w4 >> 16) | (w5 & 0xffff0000u);
      low.w = (w6 >> 16) | (w7 & 0xffff0000u);
      *(uint4*)&lh[tid * 8] = hiw;
      *(uint4*)&ll[tid * 8] = low;

      __syncthreads();   // B4: new h visible wg-wide
      #pragma unroll
      for (int r = 0; r < 4; r++) xgv[r] = xn[r];
    }
  }
}

// ---------------- CRF scan, two concurrent serial chains, tree reductions ----------------
// Blocks 0..63: alpha chain + llh.  Blocks 64..127: Viterbi chain + hist + last.
__global__ __launch_bounds__(64) void k_scan2(const int* __restrict__ lengths,
                                              const int* __restrict__ y_true,
                                              const float* __restrict__ start,
                                              const float* __restrict__ endt,
                                              const float* __restrict__ trans) {
  const int b = blockIdx.x & 63, mode = blockIdx.x >> 6, j = threadIdx.x;
  const int V = lengths[b] * 4;
  const float* em = g_em + (size_t)b * (Tn * 44);
  float tcol[11];
  #pragma unroll
  for (int i = 0; i < 11; i++) tcol[i] = (j < 11) ? trans[i * 11 + j] : 0.f;

  if (mode == 0) {
    // ---------- alpha chain ----------
    float alpha = (j < 11) ? start[j] + em[j] : -1e30f;
    for (int s0 = 1; s0 < V; s0 += 8) {
      float eb[8];
      #pragma unroll
      for (int k = 0; k < 8; k++) {
        int s = s0 + k;
        eb[k] = (j < 11 && s < Sn) ? em[s * 11 + j] : 0.f;
      }
      #pragma unroll
      for (int k = 0; k < 8; k++) {
        int s = s0 + k;
        if (s < V) {
          float av[11];
          #pragma unroll
          for (int i = 0; i < 11; i++) av[i] = __shfl(alpha, i) + tcol[i];
          float m = max11(av);
          float e0 = __expf(av[0] - m), e1 = __expf(av[1] - m);
          float e2 = __expf(av[2] - m), e3 = __expf(av[3] - m);
          float e4 = __expf(av[4] - m), e5 = __expf(av[5] - m);
          float e6 = __expf(av[6] - m), e7 = __expf(av[7] - m);
          float e8 = __expf(av[8] - m), e9 = __expf(av[9] - m);
          float e10 = __expf(av[10] - m);
          float sum = (((e0 + e1) + (e2 + e3)) + ((e4 + e5) + (e6 + e7))) +
                      ((e8 + e9) + e10);
          alpha = eb[k] + m + __logf(sum);
        }
      }
    }
    float ae = (j < 11) ? alpha + endt[j] : -1e30f;
    float av[11];
    #pragma unroll
    for (int i = 0; i < 11; i++) av[i] = __shfl(ae, i);
    float m2 = max11(av);
    float s2 = 0.f;
    #pragma unroll
    for (int i = 0; i < 11; i++) s2 += __expf(av[i] - m2);
    float logZ = m2 + __logf(s2);
    const int* y = y_true + (size_t)b * Sn;
    float part = 0.f;
    for (int s = 1 + j; s < V; s += 64) {
      int yp = y[s - 1], yc = y[s];
      part += trans[yp * 11 + yc] + em[s * 11 + yc];
    }
    #pragma unroll
    for (int off = 32; off > 0; off >>= 1) part += __shfl_down(part, off);
    if (j == 0) {
      int y0 = y[0];
      float num = start[y0] + em[y0] + part + endt[y[V - 1]];
      g_llh[b] = num - logZ;
    }
  } else {
    // ---------- Viterbi chain ----------
    float score = (j < 11) ? start[j] + em[j] : -1e30f;
    for (int s0 = 1; s0 < V; s0 += 8) {
      float eb[8];
      #pragma unroll
      for (int k = 0; k < 8; k++) {
        int s = s0 + k;
        eb[k] = (j < 11 && s < Sn) ? em[s * 11 + j] : 0.f;
      }
      #pragma unroll
      for (int k = 0; k < 8; k++) {
        int s = s0 + k;
        if (s < V) {
          float vs[11];
          #pragma unroll
          for (int i = 0; i < 11; i++) vs[i] = __shfl(score, i) + tcol[i];
          float bestv = max11(vs);
          unsigned int mask = 0;
          #pragma unroll
          for (int i = 0; i < 11; i++) mask |= (vs[i] == bestv) ? (1u << i) : 0u;
          int bi = __ffs(mask) - 1;   // first-wins: smallest index among maxima
          score = bestv + eb[k];
          if (j < 11) g_hist[(size_t)s * (Bn * NTn) + b * NTn + j] = (unsigned char)bi;
        }
      }
    }
    float se = (j < 11) ? score + endt[j] : -1e30f;
    float vs[11];
    #pragma unroll
    for (int i = 0; i < 11; i++) vs[i] = __shfl(se, i);
    float bv = max11(vs);
    unsigned int mask = 0;
    #pragma unroll
    for (int i = 0; i < 11; i++) mask |= (vs[i] == bv) ? (1u << i) : 0u;
    int bj = __ffs(mask) - 1;
    if (j == 0) g_last[b] = bj;
  }
}

// ---------------- Viterbi backtrace (double-buffered) + loss reduce ----------------
__global__ __launch_bounds__(256) void k_back(const int* __restrict__ lengths,
                                              float* __restrict__ out) {
  __shared__ unsigned char hbuf[2][64 * Bn * NTn];  // 2 x 45056 B
  const int tid = threadIdx.x;
  int carry = 0, V = 0;
  if (tid < 64) {
    float v = g_llh[tid];
    #pragma unroll
    for (int off = 32; off > 0; off >>= 1) v += __shfl_down(v, off);
    if (tid == 0) out[0] = -v / (float)Bn;
    carry = g_last[tid];
    V = lengths[tid] * 4;
    out[1 + (size_t)tid * Sn + (Sn - 1)] = (float)carry;
  }
  constexpr int CHW = 64 * Bn * NTn / 4;   // dwords per chunk
  const int nc = Sn / 64;                   // 64 chunks
  {
    const unsigned int* src =
        (const unsigned int*)(g_hist + (size_t)(nc - 1) * 64 * (Bn * NTn));
    unsigned int* dst = (unsigned int*)hbuf[(nc - 1) & 1];
    for (int i = tid; i < CHW; i += 256) dst[i] = src[i];
  }
  __syncthreads();
  for (int c = nc - 1; c >= 0; c--) {
    if (c > 0 && tid >= 64) {   // threads 64..255 prefetch chunk c-1
      const unsigned int* src =
          (const unsigned int*)(g_hist + (size_t)(c - 1) * 64 * (Bn * NTn));
      unsigned int* dst = (unsigned int*)hbuf[(c - 1) & 1];
      for (int i = tid - 64; i < CHW; i += 192) dst[i] = src[i];
    }
    if (tid < 64) {             // lanes 0..63 backtrace chunk c
      const unsigned char* hb = hbuf[c & 1];
      const int s0 = c * 64;
      for (int s = s0 + 63; s >= s0 && s >= 1; s--) {
        int pr = hb[(s - s0) * (Bn * NTn) + tid * NTn + carry];
        if (s < V) carry = pr;
        out[1 + (size_t)tid * Sn + (s - 1)] = (float)carry;
      }
    }
    __syncthreads();
  }
}

// ---------------- host ----------------
extern "C" void kernel_launch(void* const* d_in, const int* in_sizes, int n_in,
                              void* d_out, int out_size, void* d_ws, size_t ws_size,
                              hipStream_t stream) {
  (void)in_sizes; (void)n_in; (void)d_ws; (void)ws_size; (void)out_size;
  const float* x        = (const float*)d_in[0];
  const int*   y_true   = (const int*)d_in[1];
  const int*   lengths  = (const int*)d_in[2];
  const float* h0       = (const float*)d_in[3];
  const float* c0       = (const float*)d_in[4];
  const float* w_ih_l0  = (const float*)d_in[5];
  const float* w_hh_l0  = (const float*)d_in[6];
  const float* b_l0     = (const float*)d_in[7];
  const float* w_ih_l0r = (const float*)d_in[8];
  const float* w_hh_l0r = (const float*)d_in[9];
  const float* b_l0r    = (const float*)d_in[10];
  const float* w_ih_l1  = (const float*)d_in[11];
  const float* w_hh_l1  = (const float*)d_in[12];
  const float* b_l1     = (const float*)d_in[13];
  const float* w_ih_l1r = (const float*)d_in[14];
  const float* w_hh_l1r = (const float*)d_in[15];
  const float* b_l1r    = (const float*)d_in[16];
  const float* w_out    = (const float*)d_in[17];
  const float* b_out    = (const float*)d_in[18];
  const float* start_t  = (const float*)d_in[19];
  const float* end_t    = (const float*)d_in[20];
  const float* trans    = (const float*)d_in[21];
  float* out = (float*)d_out;

  auto gs = [](int n) { return dim3((n + 255) / 256); };
  dim3 b256(256);

  // weight prep + sync-flag reset (runs every call for graph-replay determinism)
  k_zinit<<<gs(4096), b256, 0, stream>>>();
  k_wswz<<<gs(4 * Gn * Hn), b256, 0, stream>>>(w_hh_l0, w_hh_l0r, w_hh_l1, w_hh_l1r);
  k_split<<<gs(131072), b256, 0, stream>>>(w_ih_l0, 1, 0, 131072);
  k_split<<<gs(131072), b256, 0, stream>>>(w_ih_l0r, 1, 131072, 131072);
  k_split<<<gs(524288), b256, 0, stream>>>(w_ih_l1, 2, 0, 524288);
  k_split<<<gs(524288), b256, 0, stream>>>(w_ih_l1r, 2, 524288, 524288);
  k_split<<<gs(22528), b256, 0, stream>>>(w_out, 3, 0, 22528);
  k_bias<<<gs(2048), b256, 0, stream>>>(b_l0, b_l0r, b_l1, b_l1r, b_out);
  k_rev<<<gs(BT), b256, 0, stream>>>(lengths);
  k_xpose<<<dim3(Tn / 32, Fn / 32, Bn), dim3(32, 8), 0, stream>>>(x);

  // layer 0
  k_gemm<0, 3><<<dim3(BT / 128, 16), b256, 0, stream>>>();
  k_rec3<<<dim3(4, 2, 8), dim3(512), 0, stream>>>(h0, c0, 0);
  // layer 1
  k_gemm<1, 3><<<dim3(BT / 128, 16), b256, 0, stream>>>();
  k_rec3<<<dim3(4, 2, 8), dim3(512), 0, stream>>>(h0, c0, 1);
  // emissions
  k_gemm<2, 3><<<dim3(BT / 128, 1), b256, 0, stream>>>();
  // CRF + viterbi (two concurrent serial chains)
  k_scan2<<<dim3(128), dim3(64), 0, stream>>>(lengths, y_true, start_t, end_t, trans);
  k_back<<<dim3(1), b256, 0, stream>>>(lengths, out);
}